// Round 3
// baseline (10009.531 us; speedup 1.0000x reference)
//
#include <hip/hip_runtime.h>

typedef unsigned short u16;
typedef unsigned int   u32;

#define TC 8          // time steps per chunk
#define NCHUNK 12     // 12*8 = 96 = T
#define CHROWS (TC*1024)

// ---- f32 weight offsets inside ws (floats), base WBASE=16 (ws[0]=dtype flag) ----
#define OFF_WFI 16
#define OFF_BFI 528
#define OFF_WZ 560
#define OFF_UZ 4656
#define OFF_WR 8752
#define OFF_UR 12848
#define OFF_WH 16944
#define OFF_UH 21040
#define OFF_BZ 25136
#define OFF_BR 25264
#define OFF_BH 25392
#define OFF_WGP 25520
#define OFF_BGP 107440
#define OFF_WGCAT 107696
#define OFF_BGCAT 304304
#define OFF_W1 305072
#define OFF_B1 321456
#define OFF_W2 321520
#define OFF_B2 321584
#define WF_TOTAL 321569            // elements handled by k_convert (relative)

// ---- byte offsets in ws ----
#define UG_BYTE   1286400ULL       // bf16 [3][256][256] = 393216 B
#define HST_BYTE  1679616ULL       // f32  [1024][256]   = 1048576 B
#define COMB_BYTE 2728192ULL       // bf16 [8192][320]   = 5242880 B
#define GI_BYTE   7971072ULL       // bf16 [8192][256]   = 4194304 B
#define AA_BYTE   12165376ULL      // bf16 [8192][768]   = 12582912 B
// total ws usage = 24748288 B ≈ 23.6 MiB

__device__ __forceinline__ float bf2f(u16 v) {
  return __uint_as_float(((u32)v) << 16);
}
__device__ __forceinline__ u16 f2bf(float f) {
  u32 x = __float_as_uint(f);
  u32 r = (x + 0x7FFFu + ((x >> 16) & 1u)) >> 16;
  return (u16)r;
}
__device__ __forceinline__ float sigm(float x) { return 1.f / (1.f + __expf(-x)); }
__device__ __forceinline__ float tanh_(float x) {
  x = fminf(fmaxf(x, -30.f), 30.f);
  float e = __expf(-2.f * x);
  return (1.f - e) / (1.f + e);
}
__device__ __forceinline__ float rdw(const void* p, int idx, bool bf) {
  return bf ? bf2f(((const u16*)p)[idx]) : ((const float*)p)[idx];
}

// ============================ D: dtype detector ============================
// bf16-packed x: dword bits 7..14 are the LOW element's bf16 exponent, ~always
// in [100,140] for N(0,1) data. f32 x: those are middle mantissa bits, uniform.
__global__ void k_detect(const u32* __restrict__ xbits, float* __restrict__ wsf) {
  __shared__ int cnt;
  if (threadIdx.x == 0) cnt = 0;
  __syncthreads();
  int good = 0;
  for (int i = 0; i < 64; i++) {
    u32 d = xbits[threadIdx.x * 64 + i];
    u32 e = (d >> 7) & 0xFFu;
    good += (e >= 100u && e <= 140u) ? 1 : 0;
  }
  atomicAdd(&cnt, good);
  __syncthreads();
  if (threadIdx.x == 0) wsf[0] = (cnt >= 8192) ? 1.0f : 0.0f;  // 1 = bf16 inputs
}

// ============================ K0: weight convert/reorg -> f32 ============================
__global__ void k_convert(
    const void* s_wfi, const void* s_bfi,
    const void* s_wz, const void* s_uz, const void* s_bz,
    const void* s_wr, const void* s_ur, const void* s_br,
    const void* s_wh, const void* s_uh, const void* s_bh,
    const void* s_wgp, const void* s_bgp,
    const void* s_wgz, const void* s_bgz,
    const void* s_wgr, const void* s_bgr,
    const void* s_wgn, const void* s_bgn,
    const void* s_w1, const void* s_b1,
    const void* s_w2, const void* s_b2,
    float* __restrict__ dst)
{
  int i = blockIdx.x * 256 + threadIdx.x;
  if (i >= WF_TOTAL) return;
  bool bf = dst[0] != 0.0f;
  int o = i;
  float v;
  if (o < 512) v = rdw(s_wfi, o, bf);
  else if ((o -= 512) < 32) v = rdw(s_bfi, o, bf);
  else if ((o -= 32) < 4096) v = rdw(s_wz, o, bf);
  else if ((o -= 4096) < 4096) v = rdw(s_uz, o, bf);
  else if ((o -= 4096) < 4096) v = rdw(s_wr, o, bf);
  else if ((o -= 4096) < 4096) v = rdw(s_ur, o, bf);
  else if ((o -= 4096) < 4096) v = rdw(s_wh, o, bf);
  else if ((o -= 4096) < 4096) v = rdw(s_uh, o, bf);
  else if ((o -= 4096) < 128) v = rdw(s_bz, o, bf);
  else if ((o -= 128) < 128) v = rdw(s_br, o, bf);
  else if ((o -= 128) < 128) v = rdw(s_bh, o, bf);
  else if ((o -= 128) < 81920) v = rdw(s_wgp, o, bf);
  else if ((o -= 81920) < 256) v = rdw(s_bgp, o, bf);
  else if ((o -= 256) < 196608) {      // wgcat [256][768] = [Wgz|Wgr|Wgn]
    int c = o / 768; int col = o - c * 768;
    int sel = col >> 8; int g = col & 255;
    const void* s = (sel == 0) ? s_wgz : (sel == 1) ? s_wgr : s_wgn;
    v = rdw(s, c * 256 + g, bf);
  }
  else if ((o -= 196608) < 768) {      // bgcat
    int sel = o >> 8; int g = o & 255;
    const void* s = (sel == 0) ? s_bgz : (sel == 1) ? s_bgr : s_bgn;
    v = rdw(s, g, bf);
  }
  else if ((o -= 768) < 16384) v = rdw(s_w1, o, bf);
  else if ((o -= 16384) < 64) v = rdw(s_b1, o, bf);
  else if ((o -= 64) < 64) v = rdw(s_w2, o, bf);
  else v = rdw(s_b2, 0, bf);
  dst[16 + i] = v;
}

// K0b: Ugz|Ugr|Ugn -> normalized bf16 copies in ws (K4 always reads bf16)
__global__ void k_convert_ug(const void* s_ugz, const void* s_ugr, const void* s_ugn,
                             const float* __restrict__ wsf, u16* __restrict__ dst) {
  int i = blockIdx.x * 256 + threadIdx.x;
  if (i >= 196608) return;
  bool bf = wsf[0] != 0.0f;
  int m = i >> 16;
  int rest = i & 65535;
  const void* s = (m == 0) ? s_ugz : (m == 1) ? s_ugr : s_ugn;
  dst[i] = bf ? ((const u16*)s)[rest] : f2bf(((const float*)s)[rest]);
}

// ============================ K1: fused per-(t,b) GNN stack ============================
#define P_PER_WG 24
__global__ __launch_bounds__(256, 2) void k_gnn(
    const void* __restrict__ xv, const void* __restrict__ adjv,
    const float* __restrict__ wsf, u16* __restrict__ comb, int prob0, int nprob)
{
  __shared__ float hsh[P_PER_WG][330];       // [p][i*33 + c], f32
  __shared__ u16 msh[P_PER_WG * 10][33];     // per-thread m row, bf16
  __shared__ u16 rsh[P_PER_WG * 10][33];     // per-thread r*h row, bf16

  int tid = threadIdx.x;
  int p = tid / 10;
  int k = tid - p * 10;
  int tb = blockIdx.x * P_PER_WG + p;        // chunk-local problem index
  bool act = (p < P_PER_WG) && (tb < nprob);
  int R = tid;
  int k33 = k * 33;
  bool isbf = wsf[0] != 0.0f;

  const float* Wfi = wsf + OFF_WFI;
  const float* Bfi = wsf + OFF_BFI;

  float h0[32];
  float ar[10];
  float hcur[32];

  if (act) {
    size_t g = (size_t)(prob0 + tb);
    float xr[16];
    if (isbf) {
      const uint4* xp = (const uint4*)((const u16*)xv + g * 160 + k * 16);
      uint4 xa = xp[0], xb = xp[1];
      u32 w;
      w = xa.x; xr[0]  = bf2f((u16)w); xr[1]  = bf2f((u16)(w >> 16));
      w = xa.y; xr[2]  = bf2f((u16)w); xr[3]  = bf2f((u16)(w >> 16));
      w = xa.z; xr[4]  = bf2f((u16)w); xr[5]  = bf2f((u16)(w >> 16));
      w = xa.w; xr[6]  = bf2f((u16)w); xr[7]  = bf2f((u16)(w >> 16));
      w = xb.x; xr[8]  = bf2f((u16)w); xr[9]  = bf2f((u16)(w >> 16));
      w = xb.y; xr[10] = bf2f((u16)w); xr[11] = bf2f((u16)(w >> 16));
      w = xb.z; xr[12] = bf2f((u16)w); xr[13] = bf2f((u16)(w >> 16));
      w = xb.w; xr[14] = bf2f((u16)w); xr[15] = bf2f((u16)(w >> 16));
    } else {
      const float4* xp = (const float4*)((const float*)xv + g * 160 + k * 16);
      float4 a = xp[0], b = xp[1], c = xp[2], d = xp[3];
      xr[0] = a.x; xr[1] = a.y; xr[2]  = a.z; xr[3]  = a.w;
      xr[4] = b.x; xr[5] = b.y; xr[6]  = b.z; xr[7]  = b.w;
      xr[8] = c.x; xr[9] = c.y; xr[10] = c.z; xr[11] = c.w;
      xr[12] = d.x; xr[13] = d.y; xr[14] = d.z; xr[15] = d.w;
    }

#pragma unroll
    for (int j = 0; j < 32; j++) h0[j] = Bfi[j];
#pragma unroll
    for (int c = 0; c < 16; c++) {
      float xc = xr[c];
#pragma unroll
      for (int j = 0; j < 32; j++) h0[j] = fmaf(xc, Wfi[c * 32 + j], h0[j]);
    }

    // adj row-normalize with self loop
    float deg = 0.f;
    if (isbf) {
      const u16* ap = (const u16*)adjv + g * 100 + k * 10;
#pragma unroll
      for (int i = 0; i < 10; i++) {
        float v = bf2f(ap[i]) + (i == k ? 1.f : 0.f);
        ar[i] = v; deg += v;
      }
    } else {
      const float* ap = (const float*)adjv + g * 100 + k * 10;
#pragma unroll
      for (int i = 0; i < 10; i++) {
        float v = ap[i] + (i == k ? 1.f : 0.f);
        ar[i] = v; deg += v;
      }
    }
    float inv = 1.f / (deg + 1e-6f);
#pragma unroll
    for (int i = 0; i < 10; i++) ar[i] *= inv;

#pragma unroll
    for (int j = 0; j < 32; j++) { hcur[j] = h0[j]; hsh[p][k33 + j] = h0[j]; }
  }
  __syncthreads();

  for (int l = 0; l < 4; l++) {
    const float* wz = wsf + OFF_WZ + l * 1024;
    const float* uz = wsf + OFF_UZ + l * 1024;
    const float* wr = wsf + OFF_WR + l * 1024;
    const float* ur = wsf + OFF_UR + l * 1024;
    const float* wh = wsf + OFF_WH + l * 1024;
    const float* uh = wsf + OFF_UH + l * 1024;
    const float* bz = wsf + OFF_BZ + l * 32;
    const float* br = wsf + OFF_BR + l * 32;
    const float* bh = wsf + OFF_BH + l * 32;

    if (act) {
      float m[32];
#pragma unroll
      for (int j = 0; j < 32; j++) m[j] = 0.f;
#pragma unroll
      for (int i = 0; i < 10; i++) {
        float ai = ar[i];
#pragma unroll
        for (int j = 0; j < 32; j++) m[j] = fmaf(ai, hsh[p][i * 33 + j], m[j]);
      }
#pragma unroll
      for (int j = 0; j < 32; j++) msh[R][j] = f2bf(m[j]);
    }
    __syncthreads();   // cross-row hsh reads complete before any h update below

    if (act) {
      float z[32], acc[32];
#pragma unroll
      for (int j = 0; j < 32; j++) acc[j] = bz[j];
      for (int c = 0; c < 32; c++) {
        float mc = bf2f(msh[R][c]);
        float hc = hsh[p][k33 + c];
#pragma unroll
        for (int j = 0; j < 32; j++)
          acc[j] = fmaf(mc, wz[c * 32 + j], fmaf(hc, uz[c * 32 + j], acc[j]));
      }
#pragma unroll
      for (int j = 0; j < 32; j++) z[j] = sigm(acc[j]);

#pragma unroll
      for (int j = 0; j < 32; j++) acc[j] = br[j];
      for (int c = 0; c < 32; c++) {
        float mc = bf2f(msh[R][c]);
        float hc = hsh[p][k33 + c];
#pragma unroll
        for (int j = 0; j < 32; j++)
          acc[j] = fmaf(mc, wr[c * 32 + j], fmaf(hc, ur[c * 32 + j], acc[j]));
      }
#pragma unroll
      for (int j = 0; j < 32; j++) {
        float r = sigm(acc[j]);
        rsh[R][j] = f2bf(r * hcur[j]);
      }

#pragma unroll
      for (int j = 0; j < 32; j++) acc[j] = bh[j];
      for (int c = 0; c < 32; c++) {
        float mc = bf2f(msh[R][c]);
        float rc = bf2f(rsh[R][c]);
#pragma unroll
        for (int j = 0; j < 32; j++)
          acc[j] = fmaf(mc, wh[c * 32 + j], fmaf(rc, uh[c * 32 + j], acc[j]));
      }

#pragma unroll
      for (int j = 0; j < 32; j++) {
        float n = tanh_(acc[j]);
        float hn = fmaf(z[j], n - hcur[j], hcur[j]) + h0[j];
        hcur[j] = hn;
        hsh[p][k33 + j] = hn;
      }
    }
    __syncthreads();
  }

  if (act) {
    u32* cp = (u32*)(comb + (size_t)tb * 320 + k * 32);
#pragma unroll
    for (int j2 = 0; j2 < 16; j2++) {
      u32 vv = (u32)f2bf(hcur[2 * j2]) | ((u32)f2bf(hcur[2 * j2 + 1]) << 16);
      cp[j2] = vv;
    }
  }
}

// ============================ K2/K3: row-parallel GEMM ============================
__global__ __launch_bounds__(256, 2) void k_gemm(
    const u16* __restrict__ in, const float* __restrict__ W, const float* __restrict__ bias,
    u16* __restrict__ out, int K, int N)
{
  extern __shared__ char smem[];
  u32* s32 = (u32*)smem;
  u16* sU = (u16*)smem;
  int tid = threadIdx.x;
  int halfK = K >> 1;
  int ldu = halfK + 1;
  int row0 = blockIdx.x * 64;
  int cg = blockIdx.y;

  const u32* gsrc = (const u32*)(in + (size_t)row0 * K);
  int tot = halfK << 6;
  for (int d = tid; d < tot; d += 256) {
    int r = d / halfK;
    int c = d - r * halfK;
    s32[r * ldu + c] = gsrc[d];
  }
  __syncthreads();

  int wv = __builtin_amdgcn_readfirstlane(tid >> 6);
  int lane = tid & 63;
  int col0 = (cg << 8) + (wv << 6);
  const u16* srow = sU + lane * (K + 2);

  float acc[64];
#pragma unroll
  for (int j = 0; j < 64; j++) acc[j] = bias[col0 + j];

  for (int kk = 0; kk < K; kk++) {
    float xk = bf2f(srow[kk]);
    const float* wp = W + (size_t)kk * N + col0;
#pragma unroll
    for (int j = 0; j < 64; j++) acc[j] = fmaf(xk, wp[j], acc[j]);
  }
  __syncthreads();

#pragma unroll
  for (int j = 0; j < 64; j++) sU[lane * 258 + (wv << 6) + j] = f2bf(acc[j]);
  __syncthreads();

  for (int d = tid; d < 8192; d += 256) {
    int r2 = d >> 7;
    int c2 = d & 127;
    u32 vv = s32[r2 * 129 + c2];
    *(u32*)(out + (size_t)(row0 + r2) * N + (cg << 8) + (c2 << 1)) = vv;
  }
}

// ============================ K4: GARU chunk (TC steps) + classifier on last ============================
__global__ __launch_bounds__(256, 1) void k_garu(
    const u16* __restrict__ aa, const u16* __restrict__ ug,
    const float* __restrict__ wsf, float* __restrict__ hstate,
    float* __restrict__ outp, int steps, int first, int last)
{
  extern __shared__ float dyn[];
  float* hs = dyn;          // [256][4] : h[c][row]
  float* rs = dyn + 1024;   // [256][4]
  int t = threadIdx.x;
  int row0 = blockIdx.x << 2;

  float h0_, h1_, h2_, h3_;
  if (first) {
    h0_ = h1_ = h2_ = h3_ = 0.f;
  } else {
    h0_ = hstate[(row0 + 0) * 256 + t];
    h1_ = hstate[(row0 + 1) * 256 + t];
    h2_ = hstate[(row0 + 2) * 256 + t];
    h3_ = hstate[(row0 + 3) * 256 + t];
  }
  *(float4*)(hs + (t << 2)) = make_float4(h0_, h1_, h2_, h3_);
  __syncthreads();

  const u16* pz = ug + t;            // Ugz
  const u16* pr = ug + 65536 + t;    // Ugr
  const u16* pn = ug + 131072 + t;   // Ugn

  for (int st = 0; st < steps; st++) {
    const u16* ab = aa + (size_t)(st * 1024 + row0) * 768 + t;

    float uz0 = 0, uz1 = 0, uz2 = 0, uz3 = 0;
    float ur0 = 0, ur1 = 0, ur2 = 0, ur3 = 0;
#pragma unroll 8
    for (int c = 0; c < 256; c++) {
      float4 hv = *(const float4*)(hs + (c << 2));
      float wzv = bf2f(pz[c << 8]);
      float wrv = bf2f(pr[c << 8]);
      uz0 = fmaf(hv.x, wzv, uz0); uz1 = fmaf(hv.y, wzv, uz1);
      uz2 = fmaf(hv.z, wzv, uz2); uz3 = fmaf(hv.w, wzv, uz3);
      ur0 = fmaf(hv.x, wrv, ur0); ur1 = fmaf(hv.y, wrv, ur1);
      ur2 = fmaf(hv.z, wrv, ur2); ur3 = fmaf(hv.w, wrv, ur3);
    }

    float az0 = bf2f(ab[0]),   az1 = bf2f(ab[768]),       az2 = bf2f(ab[1536]),       az3 = bf2f(ab[2304]);
    float aR0 = bf2f(ab[256]), aR1 = bf2f(ab[768 + 256]), aR2 = bf2f(ab[1536 + 256]), aR3 = bf2f(ab[2304 + 256]);
    float an0 = bf2f(ab[512]), an1 = bf2f(ab[768 + 512]), an2 = bf2f(ab[1536 + 512]), an3 = bf2f(ab[2304 + 512]);

    float g0 = sigm(aR0 + ur0), g1 = sigm(aR1 + ur1), g2 = sigm(aR2 + ur2), g3 = sigm(aR3 + ur3);
    *(float4*)(rs + (t << 2)) = make_float4(g0 * h0_, g1 * h1_, g2 * h2_, g3 * h3_);
    __syncthreads();

    float un0 = 0, un1 = 0, un2 = 0, un3 = 0;
#pragma unroll 8
    for (int c = 0; c < 256; c++) {
      float4 rv = *(const float4*)(rs + (c << 2));
      float wnv = bf2f(pn[c << 8]);
      un0 = fmaf(rv.x, wnv, un0); un1 = fmaf(rv.y, wnv, un1);
      un2 = fmaf(rv.z, wnv, un2); un3 = fmaf(rv.w, wnv, un3);
    }

    float gz0 = sigm(az0 + uz0), gz1 = sigm(az1 + uz1), gz2 = sigm(az2 + uz2), gz3 = sigm(az3 + uz3);
    float gn0 = tanh_(an0 + un0), gn1 = tanh_(an1 + un1), gn2 = tanh_(an2 + un2), gn3 = tanh_(an3 + un3);
    h0_ = fmaf(gz0, h0_ - gn0, gn0);
    h1_ = fmaf(gz1, h1_ - gn1, gn1);
    h2_ = fmaf(gz2, h2_ - gn2, gn2);
    h3_ = fmaf(gz3, h3_ - gn3, gn3);
    *(float4*)(hs + (t << 2)) = make_float4(h0_, h1_, h2_, h3_);
    __syncthreads();
  }

  // persist h state for next chunk
  hstate[(row0 + 0) * 256 + t] = h0_;
  hstate[(row0 + 1) * 256 + t] = h1_;
  hstate[(row0 + 2) * 256 + t] = h2_;
  hstate[(row0 + 3) * 256 + t] = h3_;

  if (last) {
    int row = t >> 6;
    int lane = t & 63;
    const float* W1 = wsf + OFF_W1;
    const float* B1 = wsf + OFF_B1;
    const float* W2 = wsf + OFF_W2;
    const float* B2 = wsf + OFF_B2;
    float hid = B1[lane];
    for (int c = 0; c < 256; c++) hid = fmaf(hs[(c << 2) + row], W1[(c << 6) + lane], hid);
    hid = fmaxf(hid, 0.f);
    float v = hid * W2[lane];
#pragma unroll
    for (int off = 32; off > 0; off >>= 1) v += __shfl_xor(v, off, 64);
    if (lane == 0) outp[row0 + row] = sigm(v + B2[0]);   // f32 output
  }
}

// ============================ launch ============================
extern "C" void kernel_launch(void* const* d_in, const int* in_sizes, int n_in,
                              void* d_out, int out_size, void* d_ws, size_t ws_size,
                              hipStream_t stream) {
  const void* x    = d_in[0];
  const void* adj  = d_in[1];
  const void* wfi  = d_in[2];
  const void* bfi  = d_in[3];
  const void* wz   = d_in[4];
  const void* uz   = d_in[5];
  const void* bz   = d_in[6];
  const void* wr   = d_in[7];
  const void* ur   = d_in[8];
  const void* br   = d_in[9];
  const void* wh   = d_in[10];
  const void* uh   = d_in[11];
  const void* bh   = d_in[12];
  const void* wgp  = d_in[13];
  const void* bgp  = d_in[14];
  const void* wgz  = d_in[15];
  const void* ugz  = d_in[16];
  const void* bgz  = d_in[17];
  const void* wgr  = d_in[18];
  const void* ugr  = d_in[19];
  const void* bgr  = d_in[20];
  const void* wgn  = d_in[21];
  const void* ugn  = d_in[22];
  const void* bgn  = d_in[23];
  const void* w1   = d_in[24];
  const void* b1   = d_in[25];
  const void* w2   = d_in[26];
  const void* b2   = d_in[27];

  float* wsf   = (float*)d_ws;
  u16* ug      = (u16*)((char*)d_ws + UG_BYTE);
  float* hst   = (float*)((char*)d_ws + HST_BYTE);
  u16* comb    = (u16*)((char*)d_ws + COMB_BYTE);
  u16* gi      = (u16*)((char*)d_ws + GI_BYTE);
  u16* aa      = (u16*)((char*)d_ws + AA_BYTE);

  k_detect<<<1, 256, 0, stream>>>((const u32*)x, wsf);

  k_convert<<<(WF_TOTAL + 255) / 256, 256, 0, stream>>>(
      wfi, bfi, wz, uz, bz, wr, ur, br, wh, uh, bh,
      wgp, bgp, wgz, bgz, wgr, bgr, wgn, bgn, w1, b1, w2, b2, wsf);

  k_convert_ug<<<(196608 + 255) / 256, 256, 0, stream>>>(ugz, ugr, ugn, wsf, ug);

  for (int c = 0; c < NCHUNK; c++) {
    int prob0 = c * CHROWS;

    k_gnn<<<(CHROWS + P_PER_WG - 1) / P_PER_WG, 256, 0, stream>>>(
        x, adj, wsf, comb, prob0, CHROWS);

    k_gemm<<<dim3(CHROWS / 64, 1), 256, 64 * 161 * 4, stream>>>(
        comb, wsf + OFF_WGP, wsf + OFF_BGP, gi, 320, 256);

    k_gemm<<<dim3(CHROWS / 64, 3), 256, 64 * 129 * 4, stream>>>(
        gi, wsf + OFF_WGCAT, wsf + OFF_BGCAT, aa, 256, 768);

    k_garu<<<256, 256, 8192, stream>>>(
        aa, ug, wsf, hst, (float*)d_out, TC, (c == 0) ? 1 : 0, (c == NCHUNK - 1) ? 1 : 0);
  }
}

// Round 4
// 2814.176 us; speedup vs baseline: 3.5568x; 3.5568x over previous
//
#include <hip/hip_runtime.h>

typedef unsigned short u16;
typedef unsigned int   u32;

typedef __attribute__((ext_vector_type(8))) short bf16x8;   // 8 bf16 (4 VGPRs)
typedef __attribute__((ext_vector_type(4))) float f32x4;

#define TB_TOTAL 98304   // T*B = 96*1024

// ---- f32 weight offsets inside ws (floats), base 16 (ws[0]=dtype flag) ----
#define OFF_WFI 16
#define OFF_BFI 528
#define OFF_WZ 560
#define OFF_UZ 4656
#define OFF_WR 8752
#define OFF_UR 12848
#define OFF_WH 16944
#define OFF_UH 21040
#define OFF_BZ 25136
#define OFF_BR 25264
#define OFF_BH 25392
#define OFF_WGP 25520
#define OFF_BGP 107440
#define OFF_WGCAT 107696
#define OFF_BGCAT 304304
#define OFF_W1 305072
#define OFF_B1 321456
#define OFF_W2 321520
#define OFF_B2 321584
#define WF_TOTAL 321569

// ---- byte offsets in ws ----
#define UG_BYTE   1286400ULL      // bf16 [3][256][256]            (393216 B)
#define BPK2_BYTE 1679616ULL      // packed Wgp frags  [81920]u16  (163840 B)
#define BPK3_BYTE 1843456ULL      // packed Wgcat frags[196608]u16 (393216 B)
#define GI_BYTE   2236672ULL      // bf16 [98304][256]             (50331648 B)
#define X_BYTE    52568320ULL     // COMB [98304][320] then AA [98304][768] (aliased; COMB dead before AA written)
// total ws usage = 203,563,264 B ≈ 194 MiB (R1 evidence: >=254 MiB available)

__device__ __forceinline__ float bf2f(u16 v) {
  return __uint_as_float(((u32)v) << 16);
}
__device__ __forceinline__ u16 f2bf(float f) {
  u32 x = __float_as_uint(f);
  u32 r = (x + 0x7FFFu + ((x >> 16) & 1u)) >> 16;
  return (u16)r;
}
__device__ __forceinline__ float sigm(float x) { return 1.f / (1.f + __expf(-x)); }
__device__ __forceinline__ float tanh_(float x) {
  x = fminf(fmaxf(x, -30.f), 30.f);
  float e = __expf(-2.f * x);
  return (1.f - e) / (1.f + e);
}
__device__ __forceinline__ float rdw(const void* p, int idx, bool bf) {
  return bf ? bf2f(((const u16*)p)[idx]) : ((const float*)p)[idx];
}

// ============================ D: dtype detector ============================
__global__ void k_detect(const u32* __restrict__ xbits, float* __restrict__ wsf) {
  __shared__ int cnt;
  if (threadIdx.x == 0) cnt = 0;
  __syncthreads();
  int good = 0;
  for (int i = 0; i < 64; i++) {
    u32 d = xbits[threadIdx.x * 64 + i];
    u32 e = (d >> 7) & 0xFFu;
    good += (e >= 100u && e <= 140u) ? 1 : 0;
  }
  atomicAdd(&cnt, good);
  __syncthreads();
  if (threadIdx.x == 0) wsf[0] = (cnt >= 8192) ? 1.0f : 0.0f;  // 1 = bf16 inputs
}

// ============================ K0: weight convert/reorg -> f32 ============================
__global__ void k_convert(
    const void* s_wfi, const void* s_bfi,
    const void* s_wz, const void* s_uz, const void* s_bz,
    const void* s_wr, const void* s_ur, const void* s_br,
    const void* s_wh, const void* s_uh, const void* s_bh,
    const void* s_wgp, const void* s_bgp,
    const void* s_wgz, const void* s_bgz,
    const void* s_wgr, const void* s_bgr,
    const void* s_wgn, const void* s_bgn,
    const void* s_w1, const void* s_b1,
    const void* s_w2, const void* s_b2,
    float* __restrict__ dst)
{
  int i = blockIdx.x * 256 + threadIdx.x;
  if (i >= WF_TOTAL) return;
  bool bf = dst[0] != 0.0f;
  int o = i;
  float v;
  if (o < 512) v = rdw(s_wfi, o, bf);
  else if ((o -= 512) < 32) v = rdw(s_bfi, o, bf);
  else if ((o -= 32) < 4096) v = rdw(s_wz, o, bf);
  else if ((o -= 4096) < 4096) v = rdw(s_uz, o, bf);
  else if ((o -= 4096) < 4096) v = rdw(s_wr, o, bf);
  else if ((o -= 4096) < 4096) v = rdw(s_ur, o, bf);
  else if ((o -= 4096) < 4096) v = rdw(s_wh, o, bf);
  else if ((o -= 4096) < 4096) v = rdw(s_uh, o, bf);
  else if ((o -= 4096) < 128) v = rdw(s_bz, o, bf);
  else if ((o -= 128) < 128) v = rdw(s_br, o, bf);
  else if ((o -= 128) < 128) v = rdw(s_bh, o, bf);
  else if ((o -= 128) < 81920) v = rdw(s_wgp, o, bf);
  else if ((o -= 81920) < 256) v = rdw(s_bgp, o, bf);
  else if ((o -= 256) < 196608) {      // wgcat [256][768] = [Wgz|Wgr|Wgn]
    int c = o / 768; int col = o - c * 768;
    int sel = col >> 8; int g = col & 255;
    const void* s = (sel == 0) ? s_wgz : (sel == 1) ? s_wgr : s_wgn;
    v = rdw(s, c * 256 + g, bf);
  }
  else if ((o -= 196608) < 768) {      // bgcat
    int sel = o >> 8; int g = o & 255;
    const void* s = (sel == 0) ? s_bgz : (sel == 1) ? s_bgr : s_bgn;
    v = rdw(s, g, bf);
  }
  else if ((o -= 768) < 16384) v = rdw(s_w1, o, bf);
  else if ((o -= 16384) < 64) v = rdw(s_b1, o, bf);
  else if ((o -= 64) < 64) v = rdw(s_w2, o, bf);
  else v = rdw(s_b2, 0, bf);
  dst[16 + i] = v;
}

// K0b: Ugz|Ugr|Ugn -> bf16 copies in ws
__global__ void k_convert_ug(const void* s_ugz, const void* s_ugr, const void* s_ugn,
                             const float* __restrict__ wsf, u16* __restrict__ dst) {
  int i = blockIdx.x * 256 + threadIdx.x;
  if (i >= 196608) return;
  bool bf = wsf[0] != 0.0f;
  int m = i >> 16;
  int rest = i & 65535;
  const void* s = (m == 0) ? s_ugz : (m == 1) ? s_ugr : s_ugn;
  dst[i] = bf ? ((const u16*)s)[rest] : f2bf(((const float*)s)[rest]);
}

// K0c: pack Wgp / [Wgz|Wgr|Wgn] into MFMA B-fragment order.
// Packed chunk (kb, cbg) holds 64 lanes x 8 bf16: element(lane,j) = W[kb*32 + (lane>>4)*8 + j][cbg*16 + (lane&15)]
__global__ void k_pack(const void* s_wgp, const void* s_wgz, const void* s_wgr, const void* s_wgn,
                       const float* __restrict__ wsf, u16* __restrict__ bpk2, u16* __restrict__ bpk3) {
  int i = blockIdx.x * 256 + threadIdx.x;
  bool bf = wsf[0] != 0.0f;
  if (i < 81920) {                       // Wgp [320][256], ncb=16
    int chunk = i >> 9;                  // kb*16 + cbg
    int rest = i & 511;                  // lane*8 + j
    int lane = rest >> 3, j = rest & 7;
    int kb = chunk >> 4, cbg = chunk & 15;
    int k = kb * 32 + (lane >> 4) * 8 + j;
    int col = cbg * 16 + (lane & 15);
    int src = k * 256 + col;
    bpk2[i] = bf ? ((const u16*)s_wgp)[src] : f2bf(((const float*)s_wgp)[src]);
  } else if (i < 81920 + 196608) {       // Wgcat [256][768], ncb=48
    int ii = i - 81920;
    int chunk = ii >> 9;
    int rest = ii & 511;
    int lane = rest >> 3, j = rest & 7;
    int kb = chunk / 48, cbg = chunk % 48;
    int k = kb * 32 + (lane >> 4) * 8 + j;
    int col = cbg * 16 + (lane & 15);    // 0..767
    int sel = col >> 8, g = col & 255;
    const void* s = (sel == 0) ? s_wgz : (sel == 1) ? s_wgr : s_wgn;
    int src = k * 256 + g;
    bpk3[ii] = bf ? ((const u16*)s)[src] : f2bf(((const float*)s)[src]);
  }
}

// ============================ K1: fused per-(t,b) GNN stack ============================
#define P_PER_WG 24
__global__ __launch_bounds__(256, 2) void k_gnn(
    const void* __restrict__ xv, const void* __restrict__ adjv,
    const float* __restrict__ wsf, u16* __restrict__ comb)
{
  __shared__ float hsh[P_PER_WG][330];       // [p][i*33 + c], f32
  __shared__ u16 msh[P_PER_WG * 10][33];     // per-thread m row, bf16
  __shared__ u16 rsh[P_PER_WG * 10][33];     // per-thread r*h row, bf16

  int tid = threadIdx.x;
  int p = tid / 10;
  int k = tid - p * 10;
  int tb = blockIdx.x * P_PER_WG + p;
  bool act = (p < P_PER_WG);
  int R = tid;
  int k33 = k * 33;
  bool isbf = wsf[0] != 0.0f;

  const float* Wfi = wsf + OFF_WFI;
  const float* Bfi = wsf + OFF_BFI;

  float h0[32];
  float ar[10];
  float hcur[32];

  if (act) {
    size_t g = (size_t)tb;
    float xr[16];
    if (isbf) {
      const uint4* xp = (const uint4*)((const u16*)xv + g * 160 + k * 16);
      uint4 xa = xp[0], xb = xp[1];
      u32 w;
      w = xa.x; xr[0]  = bf2f((u16)w); xr[1]  = bf2f((u16)(w >> 16));
      w = xa.y; xr[2]  = bf2f((u16)w); xr[3]  = bf2f((u16)(w >> 16));
      w = xa.z; xr[4]  = bf2f((u16)w); xr[5]  = bf2f((u16)(w >> 16));
      w = xa.w; xr[6]  = bf2f((u16)w); xr[7]  = bf2f((u16)(w >> 16));
      w = xb.x; xr[8]  = bf2f((u16)w); xr[9]  = bf2f((u16)(w >> 16));
      w = xb.y; xr[10] = bf2f((u16)w); xr[11] = bf2f((u16)(w >> 16));
      w = xb.z; xr[12] = bf2f((u16)w); xr[13] = bf2f((u16)(w >> 16));
      w = xb.w; xr[14] = bf2f((u16)w); xr[15] = bf2f((u16)(w >> 16));
    } else {
      const float4* xp = (const float4*)((const float*)xv + g * 160 + k * 16);
      float4 a = xp[0], b = xp[1], c = xp[2], d = xp[3];
      xr[0] = a.x; xr[1] = a.y; xr[2]  = a.z; xr[3]  = a.w;
      xr[4] = b.x; xr[5] = b.y; xr[6]  = b.z; xr[7]  = b.w;
      xr[8] = c.x; xr[9] = c.y; xr[10] = c.z; xr[11] = c.w;
      xr[12] = d.x; xr[13] = d.y; xr[14] = d.z; xr[15] = d.w;
    }

#pragma unroll
    for (int j = 0; j < 32; j++) h0[j] = Bfi[j];
#pragma unroll
    for (int c = 0; c < 16; c++) {
      float xc = xr[c];
#pragma unroll
      for (int j = 0; j < 32; j++) h0[j] = fmaf(xc, Wfi[c * 32 + j], h0[j]);
    }

    float deg = 0.f;
    if (isbf) {
      const u16* ap = (const u16*)adjv + g * 100 + k * 10;
#pragma unroll
      for (int i = 0; i < 10; i++) {
        float v = bf2f(ap[i]) + (i == k ? 1.f : 0.f);
        ar[i] = v; deg += v;
      }
    } else {
      const float* ap = (const float*)adjv + g * 100 + k * 10;
#pragma unroll
      for (int i = 0; i < 10; i++) {
        float v = ap[i] + (i == k ? 1.f : 0.f);
        ar[i] = v; deg += v;
      }
    }
    float inv = 1.f / (deg + 1e-6f);
#pragma unroll
    for (int i = 0; i < 10; i++) ar[i] *= inv;

#pragma unroll
    for (int j = 0; j < 32; j++) { hcur[j] = h0[j]; hsh[p][k33 + j] = h0[j]; }
  }
  __syncthreads();

  for (int l = 0; l < 4; l++) {
    const float* wz = wsf + OFF_WZ + l * 1024;
    const float* uz = wsf + OFF_UZ + l * 1024;
    const float* wr = wsf + OFF_WR + l * 1024;
    const float* ur = wsf + OFF_UR + l * 1024;
    const float* wh = wsf + OFF_WH + l * 1024;
    const float* uh = wsf + OFF_UH + l * 1024;
    const float* bz = wsf + OFF_BZ + l * 32;
    const float* br = wsf + OFF_BR + l * 32;
    const float* bh = wsf + OFF_BH + l * 32;

    if (act) {
      float m[32];
#pragma unroll
      for (int j = 0; j < 32; j++) m[j] = 0.f;
#pragma unroll
      for (int i = 0; i < 10; i++) {
        float ai = ar[i];
#pragma unroll
        for (int j = 0; j < 32; j++) m[j] = fmaf(ai, hsh[p][i * 33 + j], m[j]);
      }
#pragma unroll
      for (int j = 0; j < 32; j++) msh[R][j] = f2bf(m[j]);
    }
    __syncthreads();

    if (act) {
      float z[32], acc[32];
#pragma unroll
      for (int j = 0; j < 32; j++) acc[j] = bz[j];
      for (int c = 0; c < 32; c++) {
        float mc = bf2f(msh[R][c]);
        float hc = hsh[p][k33 + c];
#pragma unroll
        for (int j = 0; j < 32; j++)
          acc[j] = fmaf(mc, wz[c * 32 + j], fmaf(hc, uz[c * 32 + j], acc[j]));
      }
#pragma unroll
      for (int j = 0; j < 32; j++) z[j] = sigm(acc[j]);

#pragma unroll
      for (int j = 0; j < 32; j++) acc[j] = br[j];
      for (int c = 0; c < 32; c++) {
        float mc = bf2f(msh[R][c]);
        float hc = hsh[p][k33 + c];
#pragma unroll
        for (int j = 0; j < 32; j++)
          acc[j] = fmaf(mc, wr[c * 32 + j], fmaf(hc, ur[c * 32 + j], acc[j]));
      }
#pragma unroll
      for (int j = 0; j < 32; j++) {
        float r = sigm(acc[j]);
        rsh[R][j] = f2bf(r * hcur[j]);
      }

#pragma unroll
      for (int j = 0; j < 32; j++) acc[j] = bh[j];
      for (int c = 0; c < 32; c++) {
        float mc = bf2f(msh[R][c]);
        float rc = bf2f(rsh[R][c]);
#pragma unroll
        for (int j = 0; j < 32; j++)
          acc[j] = fmaf(mc, wh[c * 32 + j], fmaf(rc, uh[c * 32 + j], acc[j]));
      }

#pragma unroll
      for (int j = 0; j < 32; j++) {
        float n = tanh_(acc[j]);
        float hn = fmaf(z[j], n - hcur[j], hcur[j]) + h0[j];
        hcur[j] = hn;
        hsh[p][k33 + j] = hn;
      }
    }
    __syncthreads();
  }

  if (act) {
    u32* cp = (u32*)(comb + (size_t)tb * 320 + k * 32);
#pragma unroll
    for (int j2 = 0; j2 < 16; j2++) {
      u32 vv = (u32)f2bf(hcur[2 * j2]) | ((u32)f2bf(hcur[2 * j2 + 1]) << 16);
      cp[j2] = vv;
    }
  }
}

// ============================ K2/K3: MFMA GEMM ============================
// in [M][K] bf16 row-major; bpk = packed B frags; bias f32[N]; out [M][N] bf16.
// block = 4 waves; wave = 16 rows x 256 cols; grid = (M/64, N/256). K multiple of 32.
__global__ __launch_bounds__(256, 2) void k_gemm_mfma(
    const u16* __restrict__ in, const u16* __restrict__ bpk,
    const float* __restrict__ bias, u16* __restrict__ out,
    int K, int N)
{
  int tid = threadIdx.x;
  int wv = tid >> 6;
  int lane = tid & 63;
  int quad = lane >> 4;
  int l16 = lane & 15;
  long row0 = (long)blockIdx.x * 64 + wv * 16;
  int col0 = blockIdx.y << 8;
  int ncb = N >> 4;      // col-blocks in full N
  int nk = K >> 5;       // k-blocks

  f32x4 acc[16];
#pragma unroll
  for (int cb = 0; cb < 16; cb++) {
    float b = bias[col0 + cb * 16 + l16];
    acc[cb] = (f32x4){b, b, b, b};
  }

  const u16* arow = in + (row0 + l16) * K + quad * 8;   // A[m=l16][k=quad*8+j]
  for (int kb = 0; kb < nk; kb++) {
    bf16x8 af = *(const bf16x8*)(arow + kb * 32);
    const u16* bbase = bpk + ((long)(kb * ncb + (col0 >> 4)) * 64 + lane) * 8;
#pragma unroll
    for (int cb = 0; cb < 16; cb++) {
      bf16x8 bfv = *(const bf16x8*)(bbase + cb * 512);  // chunk stride 512 elems
      acc[cb] = __builtin_amdgcn_mfma_f32_16x16x32_bf16(af, bfv, acc[cb], 0, 0, 0);
    }
  }

  // D: row = row0 + quad*4 + r, col = col0 + cb*16 + l16
#pragma unroll
  for (int cb = 0; cb < 16; cb++) {
#pragma unroll
    for (int r = 0; r < 4; r++) {
      long row = row0 + quad * 4 + r;
      out[row * N + col0 + cb * 16 + l16] = f2bf(acc[cb][r]);
    }
  }
}

// ============================ K4: sequential GARU (96 steps) + classifier ============================
__global__ __launch_bounds__(256, 1) void k_garu(
    const u16* __restrict__ aa, const u16* __restrict__ ug,
    const float* __restrict__ wsf, float* __restrict__ outp)
{
  extern __shared__ float dyn[];
  float* hs = dyn;          // [256][4] : h[c][row]
  float* rs = dyn + 1024;   // [256][4]
  int t = threadIdx.x;
  int row0 = blockIdx.x << 2;

  float h0_ = 0.f, h1_ = 0.f, h2_ = 0.f, h3_ = 0.f;
  *(float4*)(hs + (t << 2)) = make_float4(0.f, 0.f, 0.f, 0.f);
  __syncthreads();

  const u16* pz = ug + t;            // Ugz col t
  const u16* pr = ug + 65536 + t;    // Ugr
  const u16* pn = ug + 131072 + t;   // Ugn

  for (int st = 0; st < 96; st++) {
    const u16* ab = aa + (size_t)(st * 1024 + row0) * 768 + t;

    float uz0 = 0, uz1 = 0, uz2 = 0, uz3 = 0;
    float ur0 = 0, ur1 = 0, ur2 = 0, ur3 = 0;
#pragma unroll 8
    for (int c = 0; c < 256; c++) {
      float4 hv = *(const float4*)(hs + (c << 2));
      float wzv = bf2f(pz[c << 8]);
      float wrv = bf2f(pr[c << 8]);
      uz0 = fmaf(hv.x, wzv, uz0); uz1 = fmaf(hv.y, wzv, uz1);
      uz2 = fmaf(hv.z, wzv, uz2); uz3 = fmaf(hv.w, wzv, uz3);
      ur0 = fmaf(hv.x, wrv, ur0); ur1 = fmaf(hv.y, wrv, ur1);
      ur2 = fmaf(hv.z, wrv, ur2); ur3 = fmaf(hv.w, wrv, ur3);
    }

    float az0 = bf2f(ab[0]),   az1 = bf2f(ab[768]),       az2 = bf2f(ab[1536]),       az3 = bf2f(ab[2304]);
    float aR0 = bf2f(ab[256]), aR1 = bf2f(ab[768 + 256]), aR2 = bf2f(ab[1536 + 256]), aR3 = bf2f(ab[2304 + 256]);
    float an0 = bf2f(ab[512]), an1 = bf2f(ab[768 + 512]), an2 = bf2f(ab[1536 + 512]), an3 = bf2f(ab[2304 + 512]);

    float g0 = sigm(aR0 + ur0), g1 = sigm(aR1 + ur1), g2 = sigm(aR2 + ur2), g3 = sigm(aR3 + ur3);
    *(float4*)(rs + (t << 2)) = make_float4(g0 * h0_, g1 * h1_, g2 * h2_, g3 * h3_);
    __syncthreads();

    float un0 = 0, un1 = 0, un2 = 0, un3 = 0;
#pragma unroll 8
    for (int c = 0; c < 256; c++) {
      float4 rv = *(const float4*)(rs + (c << 2));
      float wnv = bf2f(pn[c << 8]);
      un0 = fmaf(rv.x, wnv, un0); un1 = fmaf(rv.y, wnv, un1);
      un2 = fmaf(rv.z, wnv, un2); un3 = fmaf(rv.w, wnv, un3);
    }

    float gz0 = sigm(az0 + uz0), gz1 = sigm(az1 + uz1), gz2 = sigm(az2 + uz2), gz3 = sigm(az3 + uz3);
    float gn0 = tanh_(an0 + un0), gn1 = tanh_(an1 + un1), gn2 = tanh_(an2 + un2), gn3 = tanh_(an3 + un3);
    h0_ = fmaf(gz0, h0_ - gn0, gn0);
    h1_ = fmaf(gz1, h1_ - gn1, gn1);
    h2_ = fmaf(gz2, h2_ - gn2, gn2);
    h3_ = fmaf(gz3, h3_ - gn3, gn3);
    *(float4*)(hs + (t << 2)) = make_float4(h0_, h1_, h2_, h3_);
    __syncthreads();
  }

  // classifier: wave = one batch row
  int row = t >> 6;
  int lane = t & 63;
  const float* W1 = wsf + OFF_W1;
  const float* B1 = wsf + OFF_B1;
  const float* W2 = wsf + OFF_W2;
  const float* B2 = wsf + OFF_B2;
  float hid = B1[lane];
  for (int c = 0; c < 256; c++) hid = fmaf(hs[(c << 2) + row], W1[(c << 6) + lane], hid);
  hid = fmaxf(hid, 0.f);
  float v = hid * W2[lane];
#pragma unroll
  for (int off = 32; off > 0; off >>= 1) v += __shfl_xor(v, off, 64);
  if (lane == 0) outp[row0 + row] = sigm(v + B2[0]);   // f32 output
}

// ============================ launch ============================
extern "C" void kernel_launch(void* const* d_in, const int* in_sizes, int n_in,
                              void* d_out, int out_size, void* d_ws, size_t ws_size,
                              hipStream_t stream) {
  const void* x    = d_in[0];
  const void* adj  = d_in[1];
  const void* wfi  = d_in[2];
  const void* bfi  = d_in[3];
  const void* wz   = d_in[4];
  const void* uz   = d_in[5];
  const void* bz   = d_in[6];
  const void* wr   = d_in[7];
  const void* ur   = d_in[8];
  const void* br   = d_in[9];
  const void* wh   = d_in[10];
  const void* uh   = d_in[11];
  const void* bh   = d_in[12];
  const void* wgp  = d_in[13];
  const void* bgp  = d_in[14];
  const void* wgz  = d_in[15];
  const void* ugz  = d_in[16];
  const void* bgz  = d_in[17];
  const void* wgr  = d_in[18];
  const void* ugr  = d_in[19];
  const void* bgr  = d_in[20];
  const void* wgn  = d_in[21];
  const void* ugn  = d_in[22];
  const void* bgn  = d_in[23];
  const void* w1   = d_in[24];
  const void* b1   = d_in[25];
  const void* w2   = d_in[26];
  const void* b2   = d_in[27];

  float* wsf = (float*)d_ws;
  u16* ug    = (u16*)((char*)d_ws + UG_BYTE);
  u16* bpk2  = (u16*)((char*)d_ws + BPK2_BYTE);
  u16* bpk3  = (u16*)((char*)d_ws + BPK3_BYTE);
  u16* gi    = (u16*)((char*)d_ws + GI_BYTE);
  u16* comb  = (u16*)((char*)d_ws + X_BYTE);    // X region: COMB first...
  u16* aa    = (u16*)((char*)d_ws + X_BYTE);    // ...then AA (COMB dead by then)

  k_detect<<<1, 256, 0, stream>>>((const u32*)x, wsf);

  k_convert<<<(WF_TOTAL + 255) / 256, 256, 0, stream>>>(
      wfi, bfi, wz, uz, bz, wr, ur, br, wh, uh, bh,
      wgp, bgp, wgz, bgz, wgr, bgr, wgn, bgn, w1, b1, w2, b2, wsf);

  k_convert_ug<<<(196608 + 255) / 256, 256, 0, stream>>>(ugz, ugr, ugn, wsf, ug);

  k_pack<<<(81920 + 196608 + 255) / 256, 256, 0, stream>>>(
      wgp, wgz, wgr, wgn, wsf, bpk2, bpk3);

  // K1: all 98304 problems -> comb (X)
  k_gnn<<<TB_TOTAL / P_PER_WG, 256, 0, stream>>>(x, adj, wsf, comb);

  // K2: gi = comb @ Wgp + bgp   [98304,320]x[320,256]
  k_gemm_mfma<<<dim3(TB_TOTAL / 64, 1), 256, 0, stream>>>(
      comb, bpk2, wsf + OFF_BGP, gi, 320, 256);

  // K3: aa = gi @ [Wgz|Wgr|Wgn] + bgcat   [98304,256]x[256,768]  (writes X; comb dead)
  k_gemm_mfma<<<dim3(TB_TOTAL / 64, 3), 256, 0, stream>>>(
      gi, bpk3, wsf + OFF_BGCAT, aa, 256, 768);

  // K4: sequential GARU over 96 steps + classifier -> d_out
  k_garu<<<256, 256, 8192, stream>>>(aa, ug, wsf, (float*)d_out);
}

// Round 5
// 1679.869 us; speedup vs baseline: 5.9585x; 1.6752x over previous
//
#include <hip/hip_runtime.h>

typedef unsigned short u16;
typedef unsigned int   u32;

typedef __attribute__((ext_vector_type(8))) short bf16x8;   // 8 bf16 (4 VGPRs)
typedef __attribute__((ext_vector_type(4))) float f32x4;

#define TB_TOTAL 98304   // T*B = 96*1024

// ---- f32 weight offsets inside ws (floats), base 16 (ws[0]=dtype flag) ----
#define OFF_WFI 16
#define OFF_BFI 528
#define OFF_WZ 560
#define OFF_UZ 4656
#define OFF_WR 8752
#define OFF_UR 12848
#define OFF_WH 16944
#define OFF_UH 21040
#define OFF_BZ 25136
#define OFF_BR 25264
#define OFF_BH 25392
#define OFF_WGP 25520
#define OFF_BGP 107440
#define OFF_WGCAT 107696
#define OFF_BGCAT 304304
#define OFF_W1 305072
#define OFF_B1 321456
#define OFF_W2 321520
#define OFF_B2 321584
#define WF_TOTAL 321569

// ---- byte offsets in ws ----
#define UGPK_BYTE 1286400ULL      // GARU U frag-packed [3][16cb][8kb][64][8] u16 = 393216 B
#define BPK2_BYTE 1679616ULL      // packed Wgp frags  [81920]u16  (163840 B)
#define BPK3_BYTE 1843456ULL      // packed Wgcat frags[196608]u16 (393216 B)
#define GI_BYTE   2236672ULL      // bf16 [98304][256]             (50331648 B)
#define X_BYTE    52568320ULL     // COMB [98304][320] then AA [98304][768] (aliased; COMB dead before AA written)
// total ws usage ≈ 194 MiB

__device__ __forceinline__ float bf2f(u16 v) {
  return __uint_as_float(((u32)v) << 16);
}
__device__ __forceinline__ u16 f2bf(float f) {
  u32 x = __float_as_uint(f);
  u32 r = (x + 0x7FFFu + ((x >> 16) & 1u)) >> 16;
  return (u16)r;
}
__device__ __forceinline__ float sigm(float x) { return 1.f / (1.f + __expf(-x)); }
__device__ __forceinline__ float tanh_(float x) {
  x = fminf(fmaxf(x, -30.f), 30.f);
  float e = __expf(-2.f * x);
  return (1.f - e) / (1.f + e);
}
__device__ __forceinline__ float rdw(const void* p, int idx, bool bf) {
  return bf ? bf2f(((const u16*)p)[idx]) : ((const float*)p)[idx];
}

// ============================ D: dtype detector ============================
__global__ void k_detect(const u32* __restrict__ xbits, float* __restrict__ wsf) {
  __shared__ int cnt;
  if (threadIdx.x == 0) cnt = 0;
  __syncthreads();
  int good = 0;
  for (int i = 0; i < 64; i++) {
    u32 d = xbits[threadIdx.x * 64 + i];
    u32 e = (d >> 7) & 0xFFu;
    good += (e >= 100u && e <= 140u) ? 1 : 0;
  }
  atomicAdd(&cnt, good);
  __syncthreads();
  if (threadIdx.x == 0) wsf[0] = (cnt >= 8192) ? 1.0f : 0.0f;  // 1 = bf16 inputs
}

// ============================ K0: weight convert/reorg -> f32 ============================
__global__ void k_convert(
    const void* s_wfi, const void* s_bfi,
    const void* s_wz, const void* s_uz, const void* s_bz,
    const void* s_wr, const void* s_ur, const void* s_br,
    const void* s_wh, const void* s_uh, const void* s_bh,
    const void* s_wgp, const void* s_bgp,
    const void* s_wgz, const void* s_bgz,
    const void* s_wgr, const void* s_bgr,
    const void* s_wgn, const void* s_bgn,
    const void* s_w1, const void* s_b1,
    const void* s_w2, const void* s_b2,
    float* __restrict__ dst)
{
  int i = blockIdx.x * 256 + threadIdx.x;
  if (i >= WF_TOTAL) return;
  bool bf = dst[0] != 0.0f;
  int o = i;
  float v;
  if (o < 512) v = rdw(s_wfi, o, bf);
  else if ((o -= 512) < 32) v = rdw(s_bfi, o, bf);
  else if ((o -= 32) < 4096) v = rdw(s_wz, o, bf);
  else if ((o -= 4096) < 4096) v = rdw(s_uz, o, bf);
  else if ((o -= 4096) < 4096) v = rdw(s_wr, o, bf);
  else if ((o -= 4096) < 4096) v = rdw(s_ur, o, bf);
  else if ((o -= 4096) < 4096) v = rdw(s_wh, o, bf);
  else if ((o -= 4096) < 4096) v = rdw(s_uh, o, bf);
  else if ((o -= 4096) < 128) v = rdw(s_bz, o, bf);
  else if ((o -= 128) < 128) v = rdw(s_br, o, bf);
  else if ((o -= 128) < 128) v = rdw(s_bh, o, bf);
  else if ((o -= 128) < 81920) v = rdw(s_wgp, o, bf);
  else if ((o -= 81920) < 256) v = rdw(s_bgp, o, bf);
  else if ((o -= 256) < 196608) {      // wgcat [256][768] = [Wgz|Wgr|Wgn]
    int c = o / 768; int col = o - c * 768;
    int sel = col >> 8; int g = col & 255;
    const void* s = (sel == 0) ? s_wgz : (sel == 1) ? s_wgr : s_wgn;
    v = rdw(s, c * 256 + g, bf);
  }
  else if ((o -= 196608) < 768) {      // bgcat
    int sel = o >> 8; int g = o & 255;
    const void* s = (sel == 0) ? s_bgz : (sel == 1) ? s_bgr : s_bgn;
    v = rdw(s, g, bf);
  }
  else if ((o -= 768) < 16384) v = rdw(s_w1, o, bf);
  else if ((o -= 16384) < 64) v = rdw(s_b1, o, bf);
  else if ((o -= 64) < 64) v = rdw(s_w2, o, bf);
  else v = rdw(s_b2, 0, bf);
  dst[16 + i] = v;
}

// K0b: pack GARU U-matrices into MFMA B-fragment order [3][16cb][8kb][64][8]
__global__ void k_pack_ug(const void* s_ugz, const void* s_ugr, const void* s_ugn,
                          const float* __restrict__ wsf, u16* __restrict__ dst) {
  int i = blockIdx.x * 256 + threadIdx.x;
  if (i >= 196608) return;
  bool bf = wsf[0] != 0.0f;
  int mat = i >> 16, ii = i & 65535;
  int chunk = ii >> 9;          // cb*8 + kb
  int rest = ii & 511;          // lane*8 + j
  int lane = rest >> 3, j = rest & 7;
  int cb = chunk >> 3, kb = chunk & 7;
  int k = kb * 32 + (lane >> 4) * 8 + j;
  int g = cb * 16 + (lane & 15);
  int src = k * 256 + g;
  const void* s = (mat == 0) ? s_ugz : (mat == 1) ? s_ugr : s_ugn;
  dst[i] = bf ? ((const u16*)s)[src] : f2bf(((const float*)s)[src]);
}

// K0c: pack Wgp / [Wgz|Wgr|Wgn] into MFMA B-fragment order (for K2/K3 GEMMs)
__global__ void k_pack(const void* s_wgp, const void* s_wgz, const void* s_wgr, const void* s_wgn,
                       const float* __restrict__ wsf, u16* __restrict__ bpk2, u16* __restrict__ bpk3) {
  int i = blockIdx.x * 256 + threadIdx.x;
  bool bf = wsf[0] != 0.0f;
  if (i < 81920) {                       // Wgp [320][256], ncb=16
    int chunk = i >> 9;
    int rest = i & 511;
    int lane = rest >> 3, j = rest & 7;
    int kb = chunk >> 4, cbg = chunk & 15;
    int k = kb * 32 + (lane >> 4) * 8 + j;
    int col = cbg * 16 + (lane & 15);
    int src = k * 256 + col;
    bpk2[i] = bf ? ((const u16*)s_wgp)[src] : f2bf(((const float*)s_wgp)[src]);
  } else if (i < 81920 + 196608) {       // Wgcat [256][768], ncb=48
    int ii = i - 81920;
    int chunk = ii >> 9;
    int rest = ii & 511;
    int lane = rest >> 3, j = rest & 7;
    int kb = chunk / 48, cbg = chunk % 48;
    int k = kb * 32 + (lane >> 4) * 8 + j;
    int col = cbg * 16 + (lane & 15);
    int sel = col >> 8, g = col & 255;
    const void* s = (sel == 0) ? s_wgz : (sel == 1) ? s_wgr : s_wgn;
    int src = k * 256 + g;
    bpk3[ii] = bf ? ((const u16*)s)[src] : f2bf(((const float*)s)[src]);
  }
}

// ============================ K1: fused per-(t,b) GNN stack ============================
#define P_PER_WG 24
__global__ __launch_bounds__(256, 2) void k_gnn(
    const void* __restrict__ xv, const void* __restrict__ adjv,
    const float* __restrict__ wsf, u16* __restrict__ comb)
{
  __shared__ float hsh[P_PER_WG][330];       // [p][i*33 + c], f32
  __shared__ u16 msh[P_PER_WG * 10][33];     // per-thread m row, bf16
  __shared__ u16 rsh[P_PER_WG * 10][33];     // per-thread r*h row, bf16

  int tid = threadIdx.x;
  int p = tid / 10;
  int k = tid - p * 10;
  int tb = blockIdx.x * P_PER_WG + p;
  bool act = (p < P_PER_WG);
  int R = tid;
  int k33 = k * 33;
  bool isbf = wsf[0] != 0.0f;

  const float* Wfi = wsf + OFF_WFI;
  const float* Bfi = wsf + OFF_BFI;

  float h0[32];
  float ar[10];
  float hcur[32];

  if (act) {
    size_t g = (size_t)tb;
    float xr[16];
    if (isbf) {
      const uint4* xp = (const uint4*)((const u16*)xv + g * 160 + k * 16);
      uint4 xa = xp[0], xb = xp[1];
      u32 w;
      w = xa.x; xr[0]  = bf2f((u16)w); xr[1]  = bf2f((u16)(w >> 16));
      w = xa.y; xr[2]  = bf2f((u16)w); xr[3]  = bf2f((u16)(w >> 16));
      w = xa.z; xr[4]  = bf2f((u16)w); xr[5]  = bf2f((u16)(w >> 16));
      w = xa.w; xr[6]  = bf2f((u16)w); xr[7]  = bf2f((u16)(w >> 16));
      w = xb.x; xr[8]  = bf2f((u16)w); xr[9]  = bf2f((u16)(w >> 16));
      w = xb.y; xr[10] = bf2f((u16)w); xr[11] = bf2f((u16)(w >> 16));
      w = xb.z; xr[12] = bf2f((u16)w); xr[13] = bf2f((u16)(w >> 16));
      w = xb.w; xr[14] = bf2f((u16)w); xr[15] = bf2f((u16)(w >> 16));
    } else {
      const float4* xp = (const float4*)((const float*)xv + g * 160 + k * 16);
      float4 a = xp[0], b = xp[1], c = xp[2], d = xp[3];
      xr[0] = a.x; xr[1] = a.y; xr[2]  = a.z; xr[3]  = a.w;
      xr[4] = b.x; xr[5] = b.y; xr[6]  = b.z; xr[7]  = b.w;
      xr[8] = c.x; xr[9] = c.y; xr[10] = c.z; xr[11] = c.w;
      xr[12] = d.x; xr[13] = d.y; xr[14] = d.z; xr[15] = d.w;
    }

#pragma unroll
    for (int j = 0; j < 32; j++) h0[j] = Bfi[j];
#pragma unroll
    for (int c = 0; c < 16; c++) {
      float xc = xr[c];
#pragma unroll
      for (int j = 0; j < 32; j++) h0[j] = fmaf(xc, Wfi[c * 32 + j], h0[j]);
    }

    float deg = 0.f;
    if (isbf) {
      const u16* ap = (const u16*)adjv + g * 100 + k * 10;
#pragma unroll
      for (int i = 0; i < 10; i++) {
        float v = bf2f(ap[i]) + (i == k ? 1.f : 0.f);
        ar[i] = v; deg += v;
      }
    } else {
      const float* ap = (const float*)adjv + g * 100 + k * 10;
#pragma unroll
      for (int i = 0; i < 10; i++) {
        float v = ap[i] + (i == k ? 1.f : 0.f);
        ar[i] = v; deg += v;
      }
    }
    float inv = 1.f / (deg + 1e-6f);
#pragma unroll
    for (int i = 0; i < 10; i++) ar[i] *= inv;

#pragma unroll
    for (int j = 0; j < 32; j++) { hcur[j] = h0[j]; hsh[p][k33 + j] = h0[j]; }
  }
  __syncthreads();

  for (int l = 0; l < 4; l++) {
    const float* wz = wsf + OFF_WZ + l * 1024;
    const float* uz = wsf + OFF_UZ + l * 1024;
    const float* wr = wsf + OFF_WR + l * 1024;
    const float* ur = wsf + OFF_UR + l * 1024;
    const float* wh = wsf + OFF_WH + l * 1024;
    const float* uh = wsf + OFF_UH + l * 1024;
    const float* bz = wsf + OFF_BZ + l * 32;
    const float* br = wsf + OFF_BR + l * 32;
    const float* bh = wsf + OFF_BH + l * 32;

    if (act) {
      float m[32];
#pragma unroll
      for (int j = 0; j < 32; j++) m[j] = 0.f;
#pragma unroll
      for (int i = 0; i < 10; i++) {
        float ai = ar[i];
#pragma unroll
        for (int j = 0; j < 32; j++) m[j] = fmaf(ai, hsh[p][i * 33 + j], m[j]);
      }
#pragma unroll
      for (int j = 0; j < 32; j++) msh[R][j] = f2bf(m[j]);
    }
    __syncthreads();

    if (act) {
      float z[32], acc[32];
#pragma unroll
      for (int j = 0; j < 32; j++) acc[j] = bz[j];
      for (int c = 0; c < 32; c++) {
        float mc = bf2f(msh[R][c]);
        float hc = hsh[p][k33 + c];
#pragma unroll
        for (int j = 0; j < 32; j++)
          acc[j] = fmaf(mc, wz[c * 32 + j], fmaf(hc, uz[c * 32 + j], acc[j]));
      }
#pragma unroll
      for (int j = 0; j < 32; j++) z[j] = sigm(acc[j]);

#pragma unroll
      for (int j = 0; j < 32; j++) acc[j] = br[j];
      for (int c = 0; c < 32; c++) {
        float mc = bf2f(msh[R][c]);
        float hc = hsh[p][k33 + c];
#pragma unroll
        for (int j = 0; j < 32; j++)
          acc[j] = fmaf(mc, wr[c * 32 + j], fmaf(hc, ur[c * 32 + j], acc[j]));
      }
#pragma unroll
      for (int j = 0; j < 32; j++) {
        float r = sigm(acc[j]);
        rsh[R][j] = f2bf(r * hcur[j]);
      }

#pragma unroll
      for (int j = 0; j < 32; j++) acc[j] = bh[j];
      for (int c = 0; c < 32; c++) {
        float mc = bf2f(msh[R][c]);
        float rc = bf2f(rsh[R][c]);
#pragma unroll
        for (int j = 0; j < 32; j++)
          acc[j] = fmaf(mc, wh[c * 32 + j], fmaf(rc, uh[c * 32 + j], acc[j]));
      }

#pragma unroll
      for (int j = 0; j < 32; j++) {
        float n = tanh_(acc[j]);
        float hn = fmaf(z[j], n - hcur[j], hcur[j]) + h0[j];
        hcur[j] = hn;
        hsh[p][k33 + j] = hn;
      }
    }
    __syncthreads();
  }

  if (act) {
    u32* cp = (u32*)(comb + (size_t)tb * 320 + k * 32);
#pragma unroll
    for (int j2 = 0; j2 < 16; j2++) {
      u32 vv = (u32)f2bf(hcur[2 * j2]) | ((u32)f2bf(hcur[2 * j2 + 1]) << 16);
      cp[j2] = vv;
    }
  }
}

// ============================ K2/K3: MFMA GEMM ============================
__global__ __launch_bounds__(256, 2) void k_gemm_mfma(
    const u16* __restrict__ in, const u16* __restrict__ bpk,
    const float* __restrict__ bias, u16* __restrict__ out,
    int K, int N)
{
  int tid = threadIdx.x;
  int wv = tid >> 6;
  int lane = tid & 63;
  int quad = lane >> 4;
  int l16 = lane & 15;
  long row0 = (long)blockIdx.x * 64 + wv * 16;
  int col0 = blockIdx.y << 8;
  int ncb = N >> 4;
  int nk = K >> 5;

  f32x4 acc[16];
#pragma unroll
  for (int cb = 0; cb < 16; cb++) {
    float b = bias[col0 + cb * 16 + l16];
    acc[cb] = (f32x4){b, b, b, b};
  }

  const u16* arow = in + (row0 + l16) * K + quad * 8;
  for (int kb = 0; kb < nk; kb++) {
    bf16x8 af = *(const bf16x8*)(arow + kb * 32);
    const u16* bbase = bpk + ((long)(kb * ncb + (col0 >> 4)) * 64 + lane) * 8;
#pragma unroll
    for (int cb = 0; cb < 16; cb++) {
      bf16x8 bfv = *(const bf16x8*)(bbase + cb * 512);
      acc[cb] = __builtin_amdgcn_mfma_f32_16x16x32_bf16(af, bfv, acc[cb], 0, 0, 0);
    }
  }

#pragma unroll
  for (int cb = 0; cb < 16; cb++) {
#pragma unroll
    for (int r = 0; r < 4; r++) {
      long row = row0 + quad * 4 + r;
      out[row * N + col0 + cb * 16 + l16] = f2bf(acc[cb][r]);
    }
  }
}

// ============================ K4: MFMA GARU (96 steps) + classifier ============================
// 64 blocks x 512 threads (8 waves). Block owns 16 batch rows; wave w owns cols [w*32, w*32+32)
// for ALL gates and the h-update (owner-exclusive -> 2 barriers/step).
// Ugz/Ugr as B-frags in VGPRs (128/wave); Ugn frags in LDS (128 KB); h carry f32 in regs;
// h/rs cross-wave views as bf16 A-frag LDS buffers.
__global__ __launch_bounds__(512, 2) void k_garu_mfma(
    const u16* __restrict__ aa, const u16* __restrict__ ugpk,
    const float* __restrict__ wsf, float* __restrict__ outp)
{
  extern __shared__ u16 sm[];
  u16* sUgn = sm;                  // [16cb][8kb][64][8] = 65536 u16 (128 KB)
  u16* shA  = sm + 65536;          // h  A-frags [8kb][64][8] = 4096 u16 (8 KB)
  u16* srs  = sm + 65536 + 4096;   // rs A-frags [8kb][64][8] = 4096 u16 (8 KB)

  int tid = threadIdx.x;
  int w = tid >> 6;
  int lane = tid & 63;
  int quad = lane >> 4;
  int l16 = lane & 15;
  int row0 = blockIdx.x * 16;
  int c0 = w * 32;
  int cbase = w * 2;               // first col-block (of 16) this wave owns

  // stage Ugn frags into LDS (coalesced dwordx4)
  {
    const uint4* src = (const uint4*)(ugpk + 2 * 65536);
    uint4* dst = (uint4*)sUgn;
    for (int d = tid; d < 8192; d += 512) dst[d] = src[d];
  }
  // zero h A-frags (h0_garu = 0)
  ((uint4*)shA)[tid] = (uint4){0u, 0u, 0u, 0u};

  // resident B-frags for Ugz / Ugr
  bf16x8 fz[2][8], fr[2][8];
#pragma unroll
  for (int cb2 = 0; cb2 < 2; cb2++) {
#pragma unroll
    for (int kb = 0; kb < 8; kb++) {
      fz[cb2][kb] = *(const bf16x8*)(ugpk + ((((cbase + cb2)) * 8 + kb) * 64 + lane) * 8);
      fr[cb2][kb] = *(const bf16x8*)(ugpk + (((16 + cbase + cb2) * 8 + kb) * 64 + lane) * 8);
    }
  }

  float hold[2][4];
#pragma unroll
  for (int cb2 = 0; cb2 < 2; cb2++)
#pragma unroll
    for (int r = 0; r < 4; r++) hold[cb2][r] = 0.f;

  // precompute scatter addresses for this lane's owned cells (A-frag layout)
  int scat[2];
#pragma unroll
  for (int cb2 = 0; cb2 < 2; cb2++) {
    int col = c0 + cb2 * 16 + l16;
    scat[cb2] = (col >> 5) * 512 + ((col >> 3) & 3) * 128 + (quad * 4) * 8 + (col & 7);
  }

  __syncthreads();

  for (int st = 0; st < 96; st++) {
    const u16* ab = aa + ((size_t)st * 1024 + row0) * 768;

    // prefetch this step's aa cells (semi-coalesced u16 loads)
    float az[2][4], aR[2][4], an[2][4];
#pragma unroll
    for (int cb2 = 0; cb2 < 2; cb2++) {
      int col = c0 + cb2 * 16 + l16;
#pragma unroll
      for (int r = 0; r < 4; r++) {
        int row = quad * 4 + r;
        az[cb2][r] = bf2f(ab[row * 768 + col]);
        aR[cb2][r] = bf2f(ab[row * 768 + 256 + col]);
        an[cb2][r] = bf2f(ab[row * 768 + 512 + col]);
      }
    }

    // phase A: uz = h@Ugz, ur = h@Ugr for this wave's 32 cols
    f32x4 zero4 = (f32x4){0.f, 0.f, 0.f, 0.f};
    f32x4 uz0 = zero4, uz1 = zero4, ur0 = zero4, ur1 = zero4;
#pragma unroll
    for (int kb = 0; kb < 8; kb++) {
      bf16x8 hA = *(const bf16x8*)(shA + kb * 512 + lane * 8);
      uz0 = __builtin_amdgcn_mfma_f32_16x16x32_bf16(hA, fz[0][kb], uz0, 0, 0, 0);
      uz1 = __builtin_amdgcn_mfma_f32_16x16x32_bf16(hA, fz[1][kb], uz1, 0, 0, 0);
      ur0 = __builtin_amdgcn_mfma_f32_16x16x32_bf16(hA, fr[0][kb], ur0, 0, 0, 0);
      ur1 = __builtin_amdgcn_mfma_f32_16x16x32_bf16(hA, fr[1][kb], ur1, 0, 0, 0);
    }

    // rs = sigm(aR + ur) * h_old  -> scatter into A-frag layout
#pragma unroll
    for (int r = 0; r < 4; r++) {
      float g0 = sigm(aR[0][r] + ur0[r]);
      float g1 = sigm(aR[1][r] + ur1[r]);
      srs[scat[0] + r * 8] = f2bf(g0 * hold[0][r]);
      srs[scat[1] + r * 8] = f2bf(g1 * hold[1][r]);
    }
    __syncthreads();   // srs complete; all phase-A shA reads done

    // phase B: un = rs @ Ugn
    f32x4 un0 = zero4, un1 = zero4;
#pragma unroll
    for (int kb = 0; kb < 8; kb++) {
      bf16x8 rA = *(const bf16x8*)(srs + kb * 512 + lane * 8);
      bf16x8 b0 = *(const bf16x8*)(sUgn + ((cbase + 0) * 8 + kb) * 512 + lane * 8);
      bf16x8 b1 = *(const bf16x8*)(sUgn + ((cbase + 1) * 8 + kb) * 512 + lane * 8);
      un0 = __builtin_amdgcn_mfma_f32_16x16x32_bf16(rA, b0, un0, 0, 0, 0);
      un1 = __builtin_amdgcn_mfma_f32_16x16x32_bf16(rA, b1, un1, 0, 0, 0);
    }

    // gates + h update (owner-exclusive cells)
#pragma unroll
    for (int r = 0; r < 4; r++) {
      float gz0 = sigm(az[0][r] + uz0[r]);
      float gz1 = sigm(az[1][r] + uz1[r]);
      float gn0 = tanh_(an[0][r] + un0[r]);
      float gn1 = tanh_(an[1][r] + un1[r]);
      float h0n = fmaf(gz0, hold[0][r] - gn0, gn0);
      float h1n = fmaf(gz1, hold[1][r] - gn1, gn1);
      hold[0][r] = h0n;
      hold[1][r] = h1n;
      shA[scat[0] + r * 8] = f2bf(h0n);
      shA[scat[1] + r * 8] = f2bf(h1n);
    }
    __syncthreads();   // h visible for next step; srs reads complete
  }

  // classifier: wave handles 2 rows; lane = hidden unit j (H1=64)
  const float* W1 = wsf + OFF_W1;
  const float* B1 = wsf + OFF_B1;
  const float* W2 = wsf + OFF_W2;
  const float* B2 = wsf + OFF_B2;
#pragma unroll
  for (int rloc = 0; rloc < 2; rloc++) {
    int rr = w * 2 + rloc;
    float hid = B1[lane];
    for (int c = 0; c < 256; c++) {
      int addr = (c >> 5) * 512 + ((c >> 3) & 3) * 128 + rr * 8 + (c & 7);
      hid = fmaf(bf2f(shA[addr]), W1[c * 64 + lane], hid);   // shA addr wave-uniform -> broadcast
    }
    hid = fmaxf(hid, 0.f);
    float v = hid * W2[lane];
#pragma unroll
    for (int off = 32; off > 0; off >>= 1) v += __shfl_xor(v, off, 64);
    if (lane == 0) outp[row0 + rr] = sigm(v + B2[0]);
  }
}

// ============================ launch ============================
extern "C" void kernel_launch(void* const* d_in, const int* in_sizes, int n_in,
                              void* d_out, int out_size, void* d_ws, size_t ws_size,
                              hipStream_t stream) {
  const void* x    = d_in[0];
  const void* adj  = d_in[1];
  const void* wfi  = d_in[2];
  const void* bfi  = d_in[3];
  const void* wz   = d_in[4];
  const void* uz   = d_in[5];
  const void* bz   = d_in[6];
  const void* wr   = d_in[7];
  const void* ur   = d_in[8];
  const void* br   = d_in[9];
  const void* wh   = d_in[10];
  const void* uh   = d_in[11];
  const void* bh   = d_in[12];
  const void* wgp  = d_in[13];
  const void* bgp  = d_in[14];
  const void* wgz  = d_in[15];
  const void* ugz  = d_in[16];
  const void* bgz  = d_in[17];
  const void* wgr  = d_in[18];
  const void* ugr  = d_in[19];
  const void* bgr  = d_in[20];
  const void* wgn  = d_in[21];
  const void* ugn  = d_in[22];
  const void* bgn  = d_in[23];

  float* wsf = (float*)d_ws;
  u16* ugpk  = (u16*)((char*)d_ws + UGPK_BYTE);
  u16* bpk2  = (u16*)((char*)d_ws + BPK2_BYTE);
  u16* bpk3  = (u16*)((char*)d_ws + BPK3_BYTE);
  u16* gi    = (u16*)((char*)d_ws + GI_BYTE);
  u16* comb  = (u16*)((char*)d_ws + X_BYTE);
  u16* aa    = (u16*)((char*)d_ws + X_BYTE);

  k_detect<<<1, 256, 0, stream>>>((const u32*)x, wsf);

  k_convert<<<(WF_TOTAL + 255) / 256, 256, 0, stream>>>(
      wfi, bfi, wz, uz, bz, wr, ur, br, wh, uh, bh,
      wgp, bgp, wgz, bgz, wgr, bgr, wgn, bgn, d_in[24], d_in[25], d_in[26], d_in[27], wsf);

  k_pack_ug<<<(196608 + 255) / 256, 256, 0, stream>>>(ugz, ugr, ugn, wsf, ugpk);

  k_pack<<<(81920 + 196608 + 255) / 256, 256, 0, stream>>>(
      wgp, wgz, wgr, wgn, wsf, bpk2, bpk3);

  // K1: all 98304 problems -> comb
  k_gnn<<<TB_TOTAL / P_PER_WG, 256, 0, stream>>>(x, adj, wsf, comb);

  // K2: gi = comb @ Wgp + bgp
  k_gemm_mfma<<<dim3(TB_TOTAL / 64, 1), 256, 0, stream>>>(
      comb, bpk2, wsf + OFF_BGP, gi, 320, 256);

  // K3: aa = gi @ [Wgz|Wgr|Wgn] + bgcat (writes X; comb dead)
  k_gemm_mfma<<<dim3(TB_TOTAL / 64, 3), 256, 0, stream>>>(
      gi, bpk3, wsf + OFF_BGCAT, aa, 256, 768);

  // K4: MFMA GARU over 96 steps + classifier -> d_out  (144 KB dynamic LDS)
  k_garu_mfma<<<64, 512, 147456, stream>>>(aa, ugpk, wsf, (float*)d_out);
}

// Round 6
// 1125.561 us; speedup vs baseline: 8.8929x; 1.4925x over previous
//
#include <hip/hip_runtime.h>

typedef unsigned short u16;
typedef unsigned int   u32;

typedef __attribute__((ext_vector_type(8))) short bf16x8;   // 8 bf16 (4 VGPRs)
typedef __attribute__((ext_vector_type(4))) float f32x4;

#define TB_TOTAL 98304   // T*B = 96*1024

// ---- f32 weight offsets inside ws (floats), base 16 (ws[0]=dtype flag) ----
#define OFF_WFI 16
#define OFF_BFI 528
#define OFF_WZ 560
#define OFF_UZ 4656
#define OFF_WR 8752
#define OFF_UR 12848
#define OFF_WH 16944
#define OFF_UH 21040
#define OFF_BZ 25136
#define OFF_BR 25264
#define OFF_BH 25392
#define OFF_WGP 25520
#define OFF_BGP 107440
#define OFF_WGCAT 107696
#define OFF_BGCAT 304304
#define OFF_W1 305072
#define OFF_B1 321456
#define OFF_W2 321520
#define OFF_B2 321584
#define WF_TOTAL 321569

// ---- byte offsets in ws ----
#define UGPK_BYTE  1286400ULL     // GARU U frag-packed (393216 B)
#define BPK2_BYTE  1679616ULL     // packed Wgp frags (163840 B)
#define BPK3_BYTE  1843456ULL     // packed Wgcat frags (393216 B)
#define GNNPK_BYTE 2236672ULL     // GNN W/U frag-packed [4][6][2][64][8] u16 (49152 B)
#define GI_BYTE    2285824ULL     // bf16 [98304][256] (50331648 B)
#define X_BYTE     52617472ULL    // COMB then AA (aliased)
// total ws usage ≈ 194 MiB

__device__ __forceinline__ float bf2f(u16 v) {
  return __uint_as_float(((u32)v) << 16);
}
__device__ __forceinline__ u16 f2bf(float f) {
  u32 x = __float_as_uint(f);
  u32 r = (x + 0x7FFFu + ((x >> 16) & 1u)) >> 16;
  return (u16)r;
}
__device__ __forceinline__ float sigm(float x) { return 1.f / (1.f + __expf(-x)); }
__device__ __forceinline__ float tanh_(float x) {
  x = fminf(fmaxf(x, -30.f), 30.f);
  float e = __expf(-2.f * x);
  return (1.f - e) / (1.f + e);
}
__device__ __forceinline__ float rdw(const void* p, int idx, bool bf) {
  return bf ? bf2f(((const u16*)p)[idx]) : ((const float*)p)[idx];
}

// ============================ D: dtype detector ============================
__global__ void k_detect(const u32* __restrict__ xbits, float* __restrict__ wsf) {
  __shared__ int cnt;
  if (threadIdx.x == 0) cnt = 0;
  __syncthreads();
  int good = 0;
  for (int i = 0; i < 64; i++) {
    u32 d = xbits[threadIdx.x * 64 + i];
    u32 e = (d >> 7) & 0xFFu;
    good += (e >= 100u && e <= 140u) ? 1 : 0;
  }
  atomicAdd(&cnt, good);
  __syncthreads();
  if (threadIdx.x == 0) wsf[0] = (cnt >= 8192) ? 1.0f : 0.0f;  // 1 = bf16 inputs
}

// ============================ K0: weight convert/reorg -> f32 ============================
__global__ void k_convert(
    const void* s_wfi, const void* s_bfi,
    const void* s_wz, const void* s_uz, const void* s_bz,
    const void* s_wr, const void* s_ur, const void* s_br,
    const void* s_wh, const void* s_uh, const void* s_bh,
    const void* s_wgp, const void* s_bgp,
    const void* s_wgz, const void* s_bgz,
    const void* s_wgr, const void* s_bgr,
    const void* s_wgn, const void* s_bgn,
    const void* s_w1, const void* s_b1,
    const void* s_w2, const void* s_b2,
    float* __restrict__ dst)
{
  int i = blockIdx.x * 256 + threadIdx.x;
  if (i >= WF_TOTAL) return;
  bool bf = dst[0] != 0.0f;
  int o = i;
  float v;
  if (o < 512) v = rdw(s_wfi, o, bf);
  else if ((o -= 512) < 32) v = rdw(s_bfi, o, bf);
  else if ((o -= 32) < 4096) v = rdw(s_wz, o, bf);
  else if ((o -= 4096) < 4096) v = rdw(s_uz, o, bf);
  else if ((o -= 4096) < 4096) v = rdw(s_wr, o, bf);
  else if ((o -= 4096) < 4096) v = rdw(s_ur, o, bf);
  else if ((o -= 4096) < 4096) v = rdw(s_wh, o, bf);
  else if ((o -= 4096) < 4096) v = rdw(s_uh, o, bf);
  else if ((o -= 4096) < 128) v = rdw(s_bz, o, bf);
  else if ((o -= 128) < 128) v = rdw(s_br, o, bf);
  else if ((o -= 128) < 128) v = rdw(s_bh, o, bf);
  else if ((o -= 128) < 81920) v = rdw(s_wgp, o, bf);
  else if ((o -= 81920) < 256) v = rdw(s_bgp, o, bf);
  else if ((o -= 256) < 196608) {      // wgcat [256][768] = [Wgz|Wgr|Wgn]
    int c = o / 768; int col = o - c * 768;
    int sel = col >> 8; int g = col & 255;
    const void* s = (sel == 0) ? s_wgz : (sel == 1) ? s_wgr : s_wgn;
    v = rdw(s, c * 256 + g, bf);
  }
  else if ((o -= 196608) < 768) {      // bgcat
    int sel = o >> 8; int g = o & 255;
    const void* s = (sel == 0) ? s_bgz : (sel == 1) ? s_bgr : s_bgn;
    v = rdw(s, g, bf);
  }
  else if ((o -= 768) < 16384) v = rdw(s_w1, o, bf);
  else if ((o -= 16384) < 64) v = rdw(s_b1, o, bf);
  else if ((o -= 64) < 64) v = rdw(s_w2, o, bf);
  else v = rdw(s_b2, 0, bf);
  dst[16 + i] = v;
}

// K0b: pack GARU U-matrices into MFMA B-fragment order [3][16cb][8kb][64][8]
__global__ void k_pack_ug(const void* s_ugz, const void* s_ugr, const void* s_ugn,
                          const float* __restrict__ wsf, u16* __restrict__ dst) {
  int i = blockIdx.x * 256 + threadIdx.x;
  if (i >= 196608) return;
  bool bf = wsf[0] != 0.0f;
  int mat = i >> 16, ii = i & 65535;
  int chunk = ii >> 9;          // cb*8 + kb
  int rest = ii & 511;          // lane*8 + j
  int lane = rest >> 3, j = rest & 7;
  int cb = chunk >> 3, kb = chunk & 7;
  int k = kb * 32 + (lane >> 4) * 8 + j;
  int g = cb * 16 + (lane & 15);
  int src = k * 256 + g;
  const void* s = (mat == 0) ? s_ugz : (mat == 1) ? s_ugr : s_ugn;
  dst[i] = bf ? ((const u16*)s)[src] : f2bf(((const float*)s)[src]);
}

// K0c: pack Wgp / [Wgz|Wgr|Wgn] into MFMA B-fragment order (for K2/K3 GEMMs)
__global__ void k_pack(const void* s_wgp, const void* s_wgz, const void* s_wgr, const void* s_wgn,
                       const float* __restrict__ wsf, u16* __restrict__ bpk2, u16* __restrict__ bpk3) {
  int i = blockIdx.x * 256 + threadIdx.x;
  bool bf = wsf[0] != 0.0f;
  if (i < 81920) {                       // Wgp [320][256], ncb=16
    int chunk = i >> 9;
    int rest = i & 511;
    int lane = rest >> 3, j = rest & 7;
    int kb = chunk >> 4, cbg = chunk & 15;
    int k = kb * 32 + (lane >> 4) * 8 + j;
    int col = cbg * 16 + (lane & 15);
    int src = k * 256 + col;
    bpk2[i] = bf ? ((const u16*)s_wgp)[src] : f2bf(((const float*)s_wgp)[src]);
  } else if (i < 81920 + 196608) {       // Wgcat [256][768], ncb=48
    int ii = i - 81920;
    int chunk = ii >> 9;
    int rest = ii & 511;
    int lane = rest >> 3, j = rest & 7;
    int kb = chunk / 48, cbg = chunk % 48;
    int k = kb * 32 + (lane >> 4) * 8 + j;
    int col = cbg * 16 + (lane & 15);
    int sel = col >> 8, g = col & 255;
    const void* s = (sel == 0) ? s_wgz : (sel == 1) ? s_wgr : s_wgn;
    int src = k * 256 + g;
    bpk3[ii] = bf ? ((const u16*)s)[src] : f2bf(((const float*)s)[src]);
  }
}

// K0d: pack GNN layer matrices {Wz,Uz,Wr,Ur,Wh,Uh}[4 layers] into B-frag order
// dst[((l*6+mat)*2+cb)*512 + lane*8 + j] = M[l][k=(lane>>4)*8+j][col=cb*16+(lane&15)]
__global__ void k_pack_gnn(const void* s_wz, const void* s_uz,
                           const void* s_wr, const void* s_ur,
                           const void* s_wh, const void* s_uh,
                           const float* __restrict__ wsf, u16* __restrict__ dst) {
  int i = blockIdx.x * 256 + threadIdx.x;
  if (i >= 24576) return;
  bool bf = wsf[0] != 0.0f;
  int l = i / 6144;
  int r1 = i - l * 6144;
  int mat = r1 >> 10;
  int r2 = r1 & 1023;
  int cb = r2 >> 9;
  int r3 = r2 & 511;
  int lane = r3 >> 3, j = r3 & 7;
  int k = (lane >> 4) * 8 + j;
  int col = cb * 16 + (lane & 15);
  const void* s = (mat == 0) ? s_wz : (mat == 1) ? s_uz : (mat == 2) ? s_wr
                : (mat == 3) ? s_ur : (mat == 4) ? s_wh : s_uh;
  int src = l * 1024 + k * 32 + col;
  dst[i] = bf ? ((const u16*)s)[src] : f2bf(((const float*)s)[src]);
}

// ============================ K1: MFMA GNN stack ============================
// 256 threads / 16 problems / 160 node-rows = 10 tiles of 16; waves own 3/3/2/2 tiles.
// h carry f32 in C-layout regs; LDS bf16 row buffers (stride 40) feed agg + A-frags.
#define GP 16
#define LDST 40    // u16 stride per row (80 B, 16B-aligned, non-pow2)
__global__ __launch_bounds__(256, 2) void k_gnn_mfma(
    const void* __restrict__ xv, const void* __restrict__ adjv,
    const float* __restrict__ wsf, const u16* __restrict__ gnnpk,
    u16* __restrict__ comb)
{
  __shared__ u16 shn[160 * LDST];   // h rows (bf16)
  __shared__ u16 smm[160 * LDST];   // m rows
  __shared__ u16 srh[160 * LDST];   // r*h rows

  int tid = threadIdx.x;
  int w = tid >> 6, lane = tid & 63, quad = lane >> 4, l16 = lane & 15;
  bool isbf = wsf[0] != 0.0f;
  int base = blockIdx.x * GP;

  bool node_act = tid < 160;
  int p = tid / 10, k = tid - p * 10;

  float ar[10];

  // ---- init: h0 per node, adj row-norm ----
  if (node_act) {
    size_t g = (size_t)(base + p);
    float xr[16];
    if (isbf) {
      const uint4* xp = (const uint4*)((const u16*)xv + g * 160 + k * 16);
      uint4 xa = xp[0], xb = xp[1];
      u32 ww;
      ww = xa.x; xr[0]  = bf2f((u16)ww); xr[1]  = bf2f((u16)(ww >> 16));
      ww = xa.y; xr[2]  = bf2f((u16)ww); xr[3]  = bf2f((u16)(ww >> 16));
      ww = xa.z; xr[4]  = bf2f((u16)ww); xr[5]  = bf2f((u16)(ww >> 16));
      ww = xa.w; xr[6]  = bf2f((u16)ww); xr[7]  = bf2f((u16)(ww >> 16));
      ww = xb.x; xr[8]  = bf2f((u16)ww); xr[9]  = bf2f((u16)(ww >> 16));
      ww = xb.y; xr[10] = bf2f((u16)ww); xr[11] = bf2f((u16)(ww >> 16));
      ww = xb.z; xr[12] = bf2f((u16)ww); xr[13] = bf2f((u16)(ww >> 16));
      ww = xb.w; xr[14] = bf2f((u16)ww); xr[15] = bf2f((u16)(ww >> 16));
    } else {
      const float4* xp = (const float4*)((const float*)xv + g * 160 + k * 16);
      float4 a = xp[0], b = xp[1], c = xp[2], d = xp[3];
      xr[0] = a.x; xr[1] = a.y; xr[2]  = a.z; xr[3]  = a.w;
      xr[4] = b.x; xr[5] = b.y; xr[6]  = b.z; xr[7]  = b.w;
      xr[8] = c.x; xr[9] = c.y; xr[10] = c.z; xr[11] = c.w;
      xr[12] = d.x; xr[13] = d.y; xr[14] = d.z; xr[15] = d.w;
    }

    float h0n[32];
    const float* Wfi = wsf + OFF_WFI;
    const float* Bfi = wsf + OFF_BFI;
#pragma unroll
    for (int j = 0; j < 32; j++) h0n[j] = Bfi[j];
#pragma unroll
    for (int c = 0; c < 16; c++) {
      float xc = xr[c];
#pragma unroll
      for (int j = 0; j < 32; j++) h0n[j] = fmaf(xc, Wfi[c * 32 + j], h0n[j]);
    }

    float deg = 0.f;
    if (isbf) {
      const u16* ap = (const u16*)adjv + g * 100 + k * 10;
#pragma unroll
      for (int i = 0; i < 10; i++) {
        float v = bf2f(ap[i]) + (i == k ? 1.f : 0.f);
        ar[i] = v; deg += v;
      }
    } else {
      const float* ap = (const float*)adjv + g * 100 + k * 10;
#pragma unroll
      for (int i = 0; i < 10; i++) {
        float v = ap[i] + (i == k ? 1.f : 0.f);
        ar[i] = v; deg += v;
      }
    }
    float inv = 1.f / (deg + 1e-6f);
#pragma unroll
    for (int i = 0; i < 10; i++) ar[i] *= inv;

    u32* hd = (u32*)&shn[tid * LDST];
#pragma unroll
    for (int jj = 0; jj < 16; jj++)
      hd[jj] = (u32)f2bf(h0n[2 * jj]) | ((u32)f2bf(h0n[2 * jj + 1]) << 16);
  }
  __syncthreads();

  // ---- tile ownership + resident h0C/hC (f32, C-layout) ----
  int ntile = (w < 2) ? 3 : 2;
  int tl0 = w, tl1 = 4 + w, tl2 = 8 + w;
  int trow[3];
  trow[0] = tl0 * 16 + quad * 4; trow[1] = tl1 * 16 + quad * 4; trow[2] = tl2 * 16 + quad * 4;

  float h0c[3][8], hC[3][8];
#pragma unroll
  for (int tt = 0; tt < 3; tt++) {
    if (tt < ntile) {
#pragma unroll
      for (int cb = 0; cb < 2; cb++)
#pragma unroll
        for (int r = 0; r < 4; r++) {
          float v = bf2f(shn[(trow[tt] + r) * LDST + cb * 16 + l16]);
          h0c[tt][cb * 4 + r] = v;
          hC[tt][cb * 4 + r] = v;
        }
    }
  }

  for (int l = 0; l < 4; l++) {
    // B-frags for this layer (12 coalesced 16B loads; L2-hot)
    bf16x8 Bf[6][2];
#pragma unroll
    for (int mat = 0; mat < 6; mat++)
#pragma unroll
      for (int cb = 0; cb < 2; cb++)
        Bf[mat][cb] = *(const bf16x8*)(gnnpk + (((l * 6 + mat) * 2 + cb) * 64 + lane) * 8);

    // ---- P1: aggregation m = adj_norm @ h ----
    if (node_act) {
      float m[32];
#pragma unroll
      for (int j = 0; j < 32; j++) m[j] = 0.f;
#pragma unroll
      for (int i = 0; i < 10; i++) {
        const uint4* hr = (const uint4*)&shn[(p * 10 + i) * LDST];
        float a = ar[i];
#pragma unroll
        for (int q4 = 0; q4 < 4; q4++) {
          uint4 v = hr[q4];
          m[q4*8+0] = fmaf(a, __uint_as_float(v.x << 16), m[q4*8+0]);
          m[q4*8+1] = fmaf(a, __uint_as_float(v.x & 0xFFFF0000u), m[q4*8+1]);
          m[q4*8+2] = fmaf(a, __uint_as_float(v.y << 16), m[q4*8+2]);
          m[q4*8+3] = fmaf(a, __uint_as_float(v.y & 0xFFFF0000u), m[q4*8+3]);
          m[q4*8+4] = fmaf(a, __uint_as_float(v.z << 16), m[q4*8+4]);
          m[q4*8+5] = fmaf(a, __uint_as_float(v.z & 0xFFFF0000u), m[q4*8+5]);
          m[q4*8+6] = fmaf(a, __uint_as_float(v.w << 16), m[q4*8+6]);
          m[q4*8+7] = fmaf(a, __uint_as_float(v.w & 0xFFFF0000u), m[q4*8+7]);
        }
      }
      u32* md = (u32*)&smm[tid * LDST];
#pragma unroll
      for (int jj = 0; jj < 16; jj++)
        md[jj] = (u32)f2bf(m[2 * jj]) | ((u32)f2bf(m[2 * jj + 1]) << 16);
    }
    __syncthreads();

    // ---- P2: Cz/Cr/Cn MFMAs + z, r, rh ----
    f32x4 Cz[3][2], Cr[3][2], Cn[3][2];
    const float* bzp = wsf + OFF_BZ + l * 32;
    const float* brp = wsf + OFF_BR + l * 32;
    const float* bhp = wsf + OFF_BH + l * 32;
#pragma unroll
    for (int tt = 0; tt < 3; tt++) {
      if (tt < ntile) {
        int t = (tt == 0) ? tl0 : (tt == 1) ? tl1 : tl2;
        bf16x8 mA = *(const bf16x8*)&smm[(t * 16 + l16) * LDST + quad * 8];
        bf16x8 hA = *(const bf16x8*)&shn[(t * 16 + l16) * LDST + quad * 8];
#pragma unroll
        for (int cb = 0; cb < 2; cb++) {
          float bz = bzp[cb * 16 + l16];
          float br = brp[cb * 16 + l16];
          float bh = bhp[cb * 16 + l16];
          Cz[tt][cb] = (f32x4){bz, bz, bz, bz};
          Cr[tt][cb] = (f32x4){br, br, br, br};
          Cn[tt][cb] = (f32x4){bh, bh, bh, bh};
          Cz[tt][cb] = __builtin_amdgcn_mfma_f32_16x16x32_bf16(mA, Bf[0][cb], Cz[tt][cb], 0, 0, 0);
          Cz[tt][cb] = __builtin_amdgcn_mfma_f32_16x16x32_bf16(hA, Bf[1][cb], Cz[tt][cb], 0, 0, 0);
          Cr[tt][cb] = __builtin_amdgcn_mfma_f32_16x16x32_bf16(mA, Bf[2][cb], Cr[tt][cb], 0, 0, 0);
          Cr[tt][cb] = __builtin_amdgcn_mfma_f32_16x16x32_bf16(hA, Bf[3][cb], Cr[tt][cb], 0, 0, 0);
          Cn[tt][cb] = __builtin_amdgcn_mfma_f32_16x16x32_bf16(mA, Bf[4][cb], Cn[tt][cb], 0, 0, 0);
        }
        // gates z, r; scatter rh
#pragma unroll
        for (int cb = 0; cb < 2; cb++)
#pragma unroll
          for (int r = 0; r < 4; r++) {
            float z = sigm(Cz[tt][cb][r]);
            Cz[tt][cb][r] = z;                        // keep z in Cz regs
            float rr = sigm(Cr[tt][cb][r]);
            float rh = rr * hC[tt][cb * 4 + r];
            srh[(trow[tt] + r) * LDST + cb * 16 + l16] = f2bf(rh);
          }
      }
    }
    __syncthreads();

    // ---- P3: Cn += rh@Uh; n, h update ----
#pragma unroll
    for (int tt = 0; tt < 3; tt++) {
      if (tt < ntile) {
        int t = (tt == 0) ? tl0 : (tt == 1) ? tl1 : tl2;
        bf16x8 rA = *(const bf16x8*)&srh[(t * 16 + l16) * LDST + quad * 8];
#pragma unroll
        for (int cb = 0; cb < 2; cb++)
          Cn[tt][cb] = __builtin_amdgcn_mfma_f32_16x16x32_bf16(rA, Bf[5][cb], Cn[tt][cb], 0, 0, 0);
#pragma unroll
        for (int cb = 0; cb < 2; cb++)
#pragma unroll
          for (int r = 0; r < 4; r++) {
            float n = tanh_(Cn[tt][cb][r]);
            float h = hC[tt][cb * 4 + r];
            float z = Cz[tt][cb][r];
            h = fmaf(z, n - h, h) + h0c[tt][cb * 4 + r];
            hC[tt][cb * 4 + r] = h;
            shn[(trow[tt] + r) * LDST + cb * 16 + l16] = f2bf(h);
          }
      }
    }
    __syncthreads();
  }

  // ---- epilogue: comb rows (coalesced 16B stores) ----
  if (node_act) {
    const uint4* src = (const uint4*)&shn[tid * LDST];
    uint4* dst = (uint4*)(comb + ((size_t)base * 10 + tid) * 32);
#pragma unroll
    for (int q4 = 0; q4 < 4; q4++) dst[q4] = src[q4];
  }
}

// ============================ K2/K3: MFMA GEMM ============================
__global__ __launch_bounds__(256, 2) void k_gemm_mfma(
    const u16* __restrict__ in, const u16* __restrict__ bpk,
    const float* __restrict__ bias, u16* __restrict__ out,
    int K, int N)
{
  int tid = threadIdx.x;
  int wv = tid >> 6;
  int lane = tid & 63;
  int quad = lane >> 4;
  int l16 = lane & 15;
  long row0 = (long)blockIdx.x * 64 + wv * 16;
  int col0 = blockIdx.y << 8;
  int ncb = N >> 4;
  int nk = K >> 5;

  f32x4 acc[16];
#pragma unroll
  for (int cb = 0; cb < 16; cb++) {
    float b = bias[col0 + cb * 16 + l16];
    acc[cb] = (f32x4){b, b, b, b};
  }

  const u16* arow = in + (row0 + l16) * K + quad * 8;
  for (int kb = 0; kb < nk; kb++) {
    bf16x8 af = *(const bf16x8*)(arow + kb * 32);
    const u16* bbase = bpk + ((long)(kb * ncb + (col0 >> 4)) * 64 + lane) * 8;
#pragma unroll
    for (int cb = 0; cb < 16; cb++) {
      bf16x8 bfv = *(const bf16x8*)(bbase + cb * 512);
      acc[cb] = __builtin_amdgcn_mfma_f32_16x16x32_bf16(af, bfv, acc[cb], 0, 0, 0);
    }
  }

#pragma unroll
  for (int cb = 0; cb < 16; cb++) {
#pragma unroll
    for (int r = 0; r < 4; r++) {
      long row = row0 + quad * 4 + r;
      out[row * N + col0 + cb * 16 + l16] = f2bf(acc[cb][r]);
    }
  }
}

// ============================ K4: MFMA GARU (96 steps) + classifier ============================
__global__ __launch_bounds__(512, 2) void k_garu_mfma(
    const u16* __restrict__ aa, const u16* __restrict__ ugpk,
    const float* __restrict__ wsf, float* __restrict__ outp)
{
  extern __shared__ u16 sm[];
  u16* sUgn = sm;                  // [16cb][8kb][64][8] = 65536 u16 (128 KB)
  u16* shA  = sm + 65536;          // h  A-frags [8kb][64][8]
  u16* srs  = sm + 65536 + 4096;   // rs A-frags

  int tid = threadIdx.x;
  int w = tid >> 6;
  int lane = tid & 63;
  int quad = lane >> 4;
  int l16 = lane & 15;
  int row0 = blockIdx.x * 16;
  int c0 = w * 32;
  int cbase = w * 2;

  {
    const uint4* src = (const uint4*)(ugpk + 2 * 65536);
    uint4* dst = (uint4*)sUgn;
    for (int d = tid; d < 8192; d += 512) dst[d] = src[d];
  }
  ((uint4*)shA)[tid] = (uint4){0u, 0u, 0u, 0u};

  bf16x8 fz[2][8], fr[2][8];
#pragma unroll
  for (int cb2 = 0; cb2 < 2; cb2++) {
#pragma unroll
    for (int kb = 0; kb < 8; kb++) {
      fz[cb2][kb] = *(const bf16x8*)(ugpk + ((((cbase + cb2)) * 8 + kb) * 64 + lane) * 8);
      fr[cb2][kb] = *(const bf16x8*)(ugpk + (((16 + cbase + cb2) * 8 + kb) * 64 + lane) * 8);
    }
  }

  float hold[2][4];
#pragma unroll
  for (int cb2 = 0; cb2 < 2; cb2++)
#pragma unroll
    for (int r = 0; r < 4; r++) hold[cb2][r] = 0.f;

  int scat[2];
#pragma unroll
  for (int cb2 = 0; cb2 < 2; cb2++) {
    int col = c0 + cb2 * 16 + l16;
    scat[cb2] = (col >> 5) * 512 + ((col >> 3) & 3) * 128 + (quad * 4) * 8 + (col & 7);
  }

  __syncthreads();

  for (int st = 0; st < 96; st++) {
    const u16* ab = aa + ((size_t)st * 1024 + row0) * 768;

    float az[2][4], aR[2][4], an[2][4];
#pragma unroll
    for (int cb2 = 0; cb2 < 2; cb2++) {
      int col = c0 + cb2 * 16 + l16;
#pragma unroll
      for (int r = 0; r < 4; r++) {
        int row = quad * 4 + r;
        az[cb2][r] = bf2f(ab[row * 768 + col]);
        aR[cb2][r] = bf2f(ab[row * 768 + 256 + col]);
        an[cb2][r] = bf2f(ab[row * 768 + 512 + col]);
      }
    }

    f32x4 zero4 = (f32x4){0.f, 0.f, 0.f, 0.f};
    f32x4 uz0 = zero4, uz1 = zero4, ur0 = zero4, ur1 = zero4;
#pragma unroll
    for (int kb = 0; kb < 8; kb++) {
      bf16x8 hA = *(const bf16x8*)(shA + kb * 512 + lane * 8);
      uz0 = __builtin_amdgcn_mfma_f32_16x16x32_bf16(hA, fz[0][kb], uz0, 0, 0, 0);
      uz1 = __builtin_amdgcn_mfma_f32_16x16x32_bf16(hA, fz[1][kb], uz1, 0, 0, 0);
      ur0 = __builtin_amdgcn_mfma_f32_16x16x32_bf16(hA, fr[0][kb], ur0, 0, 0, 0);
      ur1 = __builtin_amdgcn_mfma_f32_16x16x32_bf16(hA, fr[1][kb], ur1, 0, 0, 0);
    }

#pragma unroll
    for (int r = 0; r < 4; r++) {
      float g0 = sigm(aR[0][r] + ur0[r]);
      float g1 = sigm(aR[1][r] + ur1[r]);
      srs[scat[0] + r * 8] = f2bf(g0 * hold[0][r]);
      srs[scat[1] + r * 8] = f2bf(g1 * hold[1][r]);
    }
    __syncthreads();

    f32x4 un0 = zero4, un1 = zero4;
#pragma unroll
    for (int kb = 0; kb < 8; kb++) {
      bf16x8 rA = *(const bf16x8*)(srs + kb * 512 + lane * 8);
      bf16x8 b0 = *(const bf16x8*)(sUgn + ((cbase + 0) * 8 + kb) * 512 + lane * 8);
      bf16x8 b1 = *(const bf16x8*)(sUgn + ((cbase + 1) * 8 + kb) * 512 + lane * 8);
      un0 = __builtin_amdgcn_mfma_f32_16x16x32_bf16(rA, b0, un0, 0, 0, 0);
      un1 = __builtin_amdgcn_mfma_f32_16x16x32_bf16(rA, b1, un1, 0, 0, 0);
    }

#pragma unroll
    for (int r = 0; r < 4; r++) {
      float gz0 = sigm(az[0][r] + uz0[r]);
      float gz1 = sigm(az[1][r] + uz1[r]);
      float gn0 = tanh_(an[0][r] + un0[r]);
      float gn1 = tanh_(an[1][r] + un1[r]);
      float h0n = fmaf(gz0, hold[0][r] - gn0, gn0);
      float h1n = fmaf(gz1, hold[1][r] - gn1, gn1);
      hold[0][r] = h0n;
      hold[1][r] = h1n;
      shA[scat[0] + r * 8] = f2bf(h0n);
      shA[scat[1] + r * 8] = f2bf(h1n);
    }
    __syncthreads();
  }

  const float* W1 = wsf + OFF_W1;
  const float* B1 = wsf + OFF_B1;
  const float* W2 = wsf + OFF_W2;
  const float* B2 = wsf + OFF_B2;
#pragma unroll
  for (int rloc = 0; rloc < 2; rloc++) {
    int rr = w * 2 + rloc;
    float hid = B1[lane];
    for (int c = 0; c < 256; c++) {
      int addr = (c >> 5) * 512 + ((c >> 3) & 3) * 128 + rr * 8 + (c & 7);
      hid = fmaf(bf2f(shA[addr]), W1[c * 64 + lane], hid);
    }
    hid = fmaxf(hid, 0.f);
    float v = hid * W2[lane];
#pragma unroll
    for (int off = 32; off > 0; off >>= 1) v += __shfl_xor(v, off, 64);
    if (lane == 0) outp[row0 + rr] = sigm(v + B2[0]);
  }
}

// ============================ launch ============================
extern "C" void kernel_launch(void* const* d_in, const int* in_sizes, int n_in,
                              void* d_out, int out_size, void* d_ws, size_t ws_size,
                              hipStream_t stream) {
  const void* x    = d_in[0];
  const void* adj  = d_in[1];
  const void* wfi  = d_in[2];
  const void* bfi  = d_in[3];
  const void* wz   = d_in[4];
  const void* uz   = d_in[5];
  const void* bz   = d_in[6];
  const void* wr   = d_in[7];
  const void* ur   = d_in[8];
  const void* br   = d_in[9];
  const void* wh   = d_in[10];
  const void* uh   = d_in[11];
  const void* bh   = d_in[12];
  const void* wgp  = d_in[13];
  const void* bgp  = d_in[14];
  const void* wgz  = d_in[15];
  const void* ugz  = d_in[16];
  const void* bgz  = d_in[17];
  const void* wgr  = d_in[18];
  const void* ugr  = d_in[19];
  const void* bgr  = d_in[20];
  const void* wgn  = d_in[21];
  const void* ugn  = d_in[22];
  const void* bgn  = d_in[23];

  float* wsf  = (float*)d_ws;
  u16* ugpk   = (u16*)((char*)d_ws + UGPK_BYTE);
  u16* bpk2   = (u16*)((char*)d_ws + BPK2_BYTE);
  u16* bpk3   = (u16*)((char*)d_ws + BPK3_BYTE);
  u16* gnnpk  = (u16*)((char*)d_ws + GNNPK_BYTE);
  u16* gi     = (u16*)((char*)d_ws + GI_BYTE);
  u16* comb   = (u16*)((char*)d_ws + X_BYTE);
  u16* aa     = (u16*)((char*)d_ws + X_BYTE);

  k_detect<<<1, 256, 0, stream>>>((const u32*)x, wsf);

  k_convert<<<(WF_TOTAL + 255) / 256, 256, 0, stream>>>(
      wfi, bfi, wz, uz, bz, wr, ur, br, wh, uh, bh,
      wgp, bgp, wgz, bgz, wgr, bgr, wgn, bgn, d_in[24], d_in[25], d_in[26], d_in[27], wsf);

  k_pack_ug<<<(196608 + 255) / 256, 256, 0, stream>>>(ugz, ugr, ugn, wsf, ugpk);

  k_pack<<<(81920 + 196608 + 255) / 256, 256, 0, stream>>>(
      wgp, wgz, wgr, wgn, wsf, bpk2, bpk3);

  k_pack_gnn<<<96, 256, 0, stream>>>(wz, uz, wr, ur, wh, uh, wsf, gnnpk);

  // K1: all 98304 problems -> comb
  k_gnn_mfma<<<TB_TOTAL / GP, 256, 0, stream>>>(x, adj, wsf, gnnpk, comb);

  // K2: gi = comb @ Wgp + bgp
  k_gemm_mfma<<<dim3(TB_TOTAL / 64, 1), 256, 0, stream>>>(
      comb, bpk2, wsf + OFF_BGP, gi, 320, 256);

  // K3: aa = gi @ [Wgz|Wgr|Wgn] + bgcat (writes X; comb dead)
  k_gemm_mfma<<<dim3(TB_TOTAL / 64, 3), 256, 0, stream>>>(
      gi, bpk3, wsf + OFF_BGCAT, aa, 256, 768);

  // K4: MFMA GARU over 96 steps + classifier -> d_out  (144 KB dynamic LDS)
  k_garu_mfma<<<64, 512, 147456, stream>>>(aa, ugpk, wsf, (float*)d_out);
}

// Round 7
// 999.083 us; speedup vs baseline: 10.0187x; 1.1266x over previous
//
#include <hip/hip_runtime.h>

typedef unsigned short u16;
typedef unsigned int   u32;

typedef __attribute__((ext_vector_type(8))) short bf16x8;   // 8 bf16 (4 VGPRs)
typedef __attribute__((ext_vector_type(4))) float f32x4;

#define TB_TOTAL 98304   // T*B = 96*1024

// ---- f32 weight offsets inside ws (floats), base 16 (ws[0]=dtype flag) ----
#define OFF_WFI 16
#define OFF_BFI 528
#define OFF_WZ 560
#define OFF_UZ 4656
#define OFF_WR 8752
#define OFF_UR 12848
#define OFF_WH 16944
#define OFF_UH 21040
#define OFF_BZ 25136
#define OFF_BR 25264
#define OFF_BH 25392
#define OFF_WGP 25520
#define OFF_BGP 107440
#define OFF_WGCAT 107696
#define OFF_BGCAT 304304
#define OFF_W1 305072
#define OFF_B1 321456
#define OFF_W2 321520
#define OFF_B2 321584
#define WF_TOTAL 321569

// ---- byte offsets in ws ----
#define UGPK_BYTE  1286400ULL     // GARU U frag-packed (393216 B)
#define BPK2_BYTE  1679616ULL     // packed Wgp frags (163840 B)
#define BPK3_BYTE  1843456ULL     // packed Wgcat frags (393216 B)
#define GNNPK_BYTE 2236672ULL     // GNN frag pack: 24576 layer-mats + 1024 Wfi = 25600 u16 (51200 B)
#define GI_BYTE    2287872ULL     // bf16 [98304][256] (50331648 B)
#define X_BYTE     52619520ULL    // COMB then AA (aliased)
// total ws usage ≈ 194 MiB

__device__ __forceinline__ float bf2f(u16 v) {
  return __uint_as_float(((u32)v) << 16);
}
__device__ __forceinline__ u16 f2bf(float f) {
  u32 x = __float_as_uint(f);
  u32 r = (x + 0x7FFFu + ((x >> 16) & 1u)) >> 16;
  return (u16)r;
}
__device__ __forceinline__ float sigm(float x) { return 1.f / (1.f + __expf(-x)); }
__device__ __forceinline__ float tanh_(float x) {
  x = fminf(fmaxf(x, -30.f), 30.f);
  float e = __expf(-2.f * x);
  return (1.f - e) / (1.f + e);
}
__device__ __forceinline__ float rdw(const void* p, int idx, bool bf) {
  return bf ? bf2f(((const u16*)p)[idx]) : ((const float*)p)[idx];
}

// ============================ D: dtype detector ============================
__global__ void k_detect(const u32* __restrict__ xbits, float* __restrict__ wsf) {
  __shared__ int cnt;
  if (threadIdx.x == 0) cnt = 0;
  __syncthreads();
  int good = 0;
  for (int i = 0; i < 64; i++) {
    u32 d = xbits[threadIdx.x * 64 + i];
    u32 e = (d >> 7) & 0xFFu;
    good += (e >= 100u && e <= 140u) ? 1 : 0;
  }
  atomicAdd(&cnt, good);
  __syncthreads();
  if (threadIdx.x == 0) wsf[0] = (cnt >= 8192) ? 1.0f : 0.0f;  // 1 = bf16 inputs
}

// ============================ K0: weight convert/reorg -> f32 ============================
__global__ void k_convert(
    const void* s_wfi, const void* s_bfi,
    const void* s_wz, const void* s_uz, const void* s_bz,
    const void* s_wr, const void* s_ur, const void* s_br,
    const void* s_wh, const void* s_uh, const void* s_bh,
    const void* s_wgp, const void* s_bgp,
    const void* s_wgz, const void* s_bgz,
    const void* s_wgr, const void* s_bgr,
    const void* s_wgn, const void* s_bgn,
    const void* s_w1, const void* s_b1,
    const void* s_w2, const void* s_b2,
    float* __restrict__ dst)
{
  int i = blockIdx.x * 256 + threadIdx.x;
  if (i >= WF_TOTAL) return;
  bool bf = dst[0] != 0.0f;
  int o = i;
  float v;
  if (o < 512) v = rdw(s_wfi, o, bf);
  else if ((o -= 512) < 32) v = rdw(s_bfi, o, bf);
  else if ((o -= 32) < 4096) v = rdw(s_wz, o, bf);
  else if ((o -= 4096) < 4096) v = rdw(s_uz, o, bf);
  else if ((o -= 4096) < 4096) v = rdw(s_wr, o, bf);
  else if ((o -= 4096) < 4096) v = rdw(s_ur, o, bf);
  else if ((o -= 4096) < 4096) v = rdw(s_wh, o, bf);
  else if ((o -= 4096) < 4096) v = rdw(s_uh, o, bf);
  else if ((o -= 4096) < 128) v = rdw(s_bz, o, bf);
  else if ((o -= 128) < 128) v = rdw(s_br, o, bf);
  else if ((o -= 128) < 128) v = rdw(s_bh, o, bf);
  else if ((o -= 128) < 81920) v = rdw(s_wgp, o, bf);
  else if ((o -= 81920) < 256) v = rdw(s_bgp, o, bf);
  else if ((o -= 256) < 196608) {      // wgcat [256][768] = [Wgz|Wgr|Wgn]
    int c = o / 768; int col = o - c * 768;
    int sel = col >> 8; int g = col & 255;
    const void* s = (sel == 0) ? s_wgz : (sel == 1) ? s_wgr : s_wgn;
    v = rdw(s, c * 256 + g, bf);
  }
  else if ((o -= 196608) < 768) {      // bgcat
    int sel = o >> 8; int g = o & 255;
    const void* s = (sel == 0) ? s_bgz : (sel == 1) ? s_bgr : s_bgn;
    v = rdw(s, g, bf);
  }
  else if ((o -= 768) < 16384) v = rdw(s_w1, o, bf);
  else if ((o -= 16384) < 64) v = rdw(s_b1, o, bf);
  else if ((o -= 64) < 64) v = rdw(s_w2, o, bf);
  else v = rdw(s_b2, 0, bf);
  dst[16 + i] = v;
}

// K0b: pack GARU U-matrices into MFMA B-fragment order [3][16cb][8kb][64][8]
__global__ void k_pack_ug(const void* s_ugz, const void* s_ugr, const void* s_ugn,
                          const float* __restrict__ wsf, u16* __restrict__ dst) {
  int i = blockIdx.x * 256 + threadIdx.x;
  if (i >= 196608) return;
  bool bf = wsf[0] != 0.0f;
  int mat = i >> 16, ii = i & 65535;
  int chunk = ii >> 9;          // cb*8 + kb
  int rest = ii & 511;          // lane*8 + j
  int lane = rest >> 3, j = rest & 7;
  int cb = chunk >> 3, kb = chunk & 7;
  int k = kb * 32 + (lane >> 4) * 8 + j;
  int g = cb * 16 + (lane & 15);
  int src = k * 256 + g;
  const void* s = (mat == 0) ? s_ugz : (mat == 1) ? s_ugr : s_ugn;
  dst[i] = bf ? ((const u16*)s)[src] : f2bf(((const float*)s)[src]);
}

// K0c: pack Wgp / [Wgz|Wgr|Wgn] into MFMA B-fragment order (for K2/K3 GEMMs)
__global__ void k_pack(const void* s_wgp, const void* s_wgz, const void* s_wgr, const void* s_wgn,
                       const float* __restrict__ wsf, u16* __restrict__ bpk2, u16* __restrict__ bpk3) {
  int i = blockIdx.x * 256 + threadIdx.x;
  bool bf = wsf[0] != 0.0f;
  if (i < 81920) {                       // Wgp [320][256], ncb=16
    int chunk = i >> 9;
    int rest = i & 511;
    int lane = rest >> 3, j = rest & 7;
    int kb = chunk >> 4, cbg = chunk & 15;
    int k = kb * 32 + (lane >> 4) * 8 + j;
    int col = cbg * 16 + (lane & 15);
    int src = k * 256 + col;
    bpk2[i] = bf ? ((const u16*)s_wgp)[src] : f2bf(((const float*)s_wgp)[src]);
  } else if (i < 81920 + 196608) {       // Wgcat [256][768], ncb=48
    int ii = i - 81920;
    int chunk = ii >> 9;
    int rest = ii & 511;
    int lane = rest >> 3, j = rest & 7;
    int kb = chunk / 48, cbg = chunk % 48;
    int k = kb * 32 + (lane >> 4) * 8 + j;
    int col = cbg * 16 + (lane & 15);
    int sel = col >> 8, g = col & 255;
    const void* s = (sel == 0) ? s_wgz : (sel == 1) ? s_wgr : s_wgn;
    int src = k * 256 + g;
    bpk3[ii] = bf ? ((const u16*)s)[src] : f2bf(((const float*)s)[src]);
  }
}

// K0d: pack GNN layer matrices {Wz,Uz,Wr,Ur,Wh,Uh}[4] + Wfi into B-frag order
__global__ void k_pack_gnn(const void* s_wfi,
                           const void* s_wz, const void* s_uz,
                           const void* s_wr, const void* s_ur,
                           const void* s_wh, const void* s_uh,
                           const float* __restrict__ wsf, u16* __restrict__ dst) {
  int i = blockIdx.x * 256 + threadIdx.x;
  if (i >= 25600) return;
  bool bf = wsf[0] != 0.0f;
  if (i < 24576) {
    int l = i / 6144;
    int r1 = i - l * 6144;
    int mat = r1 >> 10;
    int r2 = r1 & 1023;
    int cb = r2 >> 9;
    int r3 = r2 & 511;
    int lane = r3 >> 3, j = r3 & 7;
    int k = (lane >> 4) * 8 + j;
    int col = cb * 16 + (lane & 15);
    const void* s = (mat == 0) ? s_wz : (mat == 1) ? s_uz : (mat == 2) ? s_wr
                  : (mat == 3) ? s_ur : (mat == 4) ? s_wh : s_uh;
    int src = l * 1024 + k * 32 + col;
    dst[i] = bf ? ((const u16*)s)[src] : f2bf(((const float*)s)[src]);
  } else {                                // Wfi [16][32] B-frags [2][64][8]
    int ii = i - 24576;
    int cb = ii >> 9;
    int r3 = ii & 511;
    int lane = r3 >> 3, j = r3 & 7;
    int k = (lane >> 4) * 8 + j;          // 0..31, valid <16
    int col = cb * 16 + (lane & 15);
    dst[i] = (k < 16) ? (bf ? ((const u16*)s_wfi)[k * 32 + col]
                            : f2bf(((const float*)s_wfi)[k * 32 + col]))
                      : (u16)0;
  }
}

// ============================ K1: MFMA GNN stack v2 ============================
// 256 threads / 16 problems / 160 node-rows = 10 tiles; waves own 3/3/2/2 tiles.
// Aggregation + h0-init also on MFMA (adj A-frags + compact h B-frags in LDS).
// h carry f32 in C-layout regs; 2 barriers/layer.
#define GP 16
#define LDST 40    // u16 stride per row (80 B)
__global__ __launch_bounds__(256, 2) void k_gnn_mfma(
    const void* __restrict__ xv, const void* __restrict__ adjv,
    const float* __restrict__ wsf, const u16* __restrict__ gnnpk,
    u16* __restrict__ comb)
{
  __shared__ u16 shn[160 * LDST];        // h rows bf16
  __shared__ u16 smm[160 * LDST];        // m rows, then rh rows (shared)
  __shared__ u16 hbf[16 * 2 * 32 * 8];   // h B-frags, compact 32-lane (16384 u16)
  __shared__ u16 adjf[16 * 32 * 8];      // adj A-frags, compact (4096 u16)

  int tid = threadIdx.x;
  int w = tid >> 6, lane = tid & 63, quad = lane >> 4, l16 = lane & 15;
  bool isbf = wsf[0] != 0.0f;
  long base = (long)blockIdx.x * GP;

  const bf16x8 z8 = {0, 0, 0, 0, 0, 0, 0, 0};
  const f32x4 zf = {0.f, 0.f, 0.f, 0.f};

  // ---- phase 0: zero frag buffers (dead slots must be 0) ----
  {
    u32* hz = (u32*)hbf;
#pragma unroll
    for (int i = 0; i < 32; i++) hz[tid + 256 * i] = 0u;
    u32* az = (u32*)adjf;
#pragma unroll
    for (int i = 0; i < 8; i++) az[tid + 256 * i] = 0u;
  }
  __syncthreads();

  // ---- phase 0b: adj A-frag scatter (160 threads) ----
  if (tid < 160) {
    int p = tid / 10, k = tid - p * 10;
    float ar[10];
    float deg = 0.f;
    if (isbf) {
      const u16* ap = (const u16*)adjv + (base + p) * 100 + k * 10;
#pragma unroll
      for (int i = 0; i < 10; i++) {
        float v = bf2f(ap[i]) + (i == k ? 1.f : 0.f);
        ar[i] = v; deg += v;
      }
    } else {
      const float* ap = (const float*)adjv + (base + p) * 100 + k * 10;
#pragma unroll
      for (int i = 0; i < 10; i++) {
        float v = ap[i] + (i == k ? 1.f : 0.f);
        ar[i] = v; deg += v;
      }
    }
    float inv = 1.f / (deg + 1e-6f);
#pragma unroll
    for (int i = 0; i < 10; i++)
      adjf[(p * 32 + ((i >> 3) << 4) + k) * 8 + (i & 7)] = f2bf(ar[i] * inv);
  }

  // ---- tiles + h0 via MFMA ----
  int ntile = (w < 2) ? 3 : 2;
  int tiles[3] = {w, 4 + w, 8 + w};

  bf16x8 wfiF[2];
  wfiF[0] = *(const bf16x8*)(gnnpk + 24576 + (size_t)lane * 8);
  wfiF[1] = *(const bf16x8*)(gnnpk + 24576 + (size_t)(64 + lane) * 8);
  float bfi0 = wsf[OFF_BFI + l16];
  float bfi1 = wsf[OFF_BFI + 16 + l16];

  f32x4 h0C[3][2], hC[3][2];
#pragma unroll
  for (int tt = 0; tt < 3; tt++) {
    if (tt < ntile) {
      int t = tiles[tt];
      int grow = t * 16 + l16;
      bf16x8 xA = z8;
      if (quad < 2) {
        size_t xoff = ((size_t)(base * 10 + grow) << 4) + quad * 8;
        if (isbf) {
          xA = *(const bf16x8*)((const u16*)xv + xoff);
        } else {
          const float* xf = (const float*)xv + xoff;
          union { u16 e[8]; bf16x8 v; } ux;
#pragma unroll
          for (int j = 0; j < 8; j++) ux.e[j] = f2bf(xf[j]);
          xA = ux.v;
        }
      }
      f32x4 c0 = {bfi0, bfi0, bfi0, bfi0};
      f32x4 c1 = {bfi1, bfi1, bfi1, bfi1};
      h0C[tt][0] = __builtin_amdgcn_mfma_f32_16x16x32_bf16(xA, wfiF[0], c0, 0, 0, 0);
      h0C[tt][1] = __builtin_amdgcn_mfma_f32_16x16x32_bf16(xA, wfiF[1], c1, 0, 0, 0);
      int trowv = t * 16 + quad * 4;
#pragma unroll
      for (int cb = 0; cb < 2; cb++) {
#pragma unroll
        for (int r = 0; r < 4; r++) {
          float hv = h0C[tt][cb][r];
          hC[tt][cb][r] = hv;
          u16 hb = f2bf(hv);
          int g2 = trowv + r;
          shn[g2 * LDST + cb * 16 + l16] = hb;
          int p2 = (g2 * 205) >> 11;          // g2/10 for g2<160
          int nd = g2 - p2 * 10;
          hbf[((p2 * 2 + cb) * 32 + ((nd >> 3) << 4) + l16) * 8 + (nd & 7)] = hb;
        }
      }
    }
  }
  __syncthreads();   // adjf + hbf + shn ready

  // ---- layers ----
  for (int l = 0; l < 4; l++) {
    bf16x8 Bf[6][2];
#pragma unroll
    for (int mat = 0; mat < 6; mat++)
#pragma unroll
      for (int cb = 0; cb < 2; cb++)
        Bf[mat][cb] = *(const bf16x8*)(gnnpk + (((l * 6 + mat) * 2 + cb) * 64 + lane) * 8);

    // P1: aggregation via MFMA (wave owns problems 4w..4w+3)
#pragma unroll
    for (int pp = 0; pp < 4; pp++) {
      int p = w * 4 + pp;
      bf16x8 aA = z8, hB0 = z8, hB1 = z8;
      if (lane < 32) {
        aA  = *(const bf16x8*)&adjf[(p * 32 + lane) * 8];
        hB0 = *(const bf16x8*)&hbf[((p * 2 + 0) * 32 + lane) * 8];
        hB1 = *(const bf16x8*)&hbf[((p * 2 + 1) * 32 + lane) * 8];
      }
      f32x4 m0 = __builtin_amdgcn_mfma_f32_16x16x32_bf16(aA, hB0, zf, 0, 0, 0);
      f32x4 m1 = __builtin_amdgcn_mfma_f32_16x16x32_bf16(aA, hB1, zf, 0, 0, 0);
      int rowb = quad * 4;
#pragma unroll
      for (int r = 0; r < 4; r++) {
        int row = rowb + r;
        if (row < 10) {
          smm[(p * 10 + row) * LDST + l16] = f2bf(m0[r]);
          smm[(p * 10 + row) * LDST + 16 + l16] = f2bf(m1[r]);
        }
      }
    }
    __syncthreads();   // m rows complete (cross-wave)

    // P2+P3 fused per tile (rh is wave-local)
    const float* bzp = wsf + OFF_BZ + l * 32;
    const float* brp = wsf + OFF_BR + l * 32;
    const float* bhp = wsf + OFF_BH + l * 32;
#pragma unroll
    for (int tt = 0; tt < 3; tt++) {
      if (tt < ntile) {
        int t = tiles[tt];
        bf16x8 mA = *(const bf16x8*)&smm[(t * 16 + l16) * LDST + quad * 8];
        bf16x8 hA = *(const bf16x8*)&shn[(t * 16 + l16) * LDST + quad * 8];
        int trowv = t * 16 + quad * 4;
        f32x4 Cz[2], Cn[2];
#pragma unroll
        for (int cb = 0; cb < 2; cb++) {
          float bz = bzp[cb * 16 + l16];
          float br = brp[cb * 16 + l16];
          float bh = bhp[cb * 16 + l16];
          f32x4 cz = {bz, bz, bz, bz};
          f32x4 cr = {br, br, br, br};
          f32x4 cn = {bh, bh, bh, bh};
          cz = __builtin_amdgcn_mfma_f32_16x16x32_bf16(mA, Bf[0][cb], cz, 0, 0, 0);
          cz = __builtin_amdgcn_mfma_f32_16x16x32_bf16(hA, Bf[1][cb], cz, 0, 0, 0);
          cr = __builtin_amdgcn_mfma_f32_16x16x32_bf16(mA, Bf[2][cb], cr, 0, 0, 0);
          cr = __builtin_amdgcn_mfma_f32_16x16x32_bf16(hA, Bf[3][cb], cr, 0, 0, 0);
          cn = __builtin_amdgcn_mfma_f32_16x16x32_bf16(mA, Bf[4][cb], cn, 0, 0, 0);
#pragma unroll
          for (int r = 0; r < 4; r++) {
            float z = sigm(cz[r]);
            float rr = sigm(cr[r]);
            cz[r] = z;
            smm[(trowv + r) * LDST + cb * 16 + l16] = f2bf(rr * hC[tt][cb][r]);
          }
          Cz[cb] = cz; Cn[cb] = cn;
        }
        // rh of this tile fully written by this wave -> read as A-frag
        bf16x8 rA = *(const bf16x8*)&smm[(t * 16 + l16) * LDST + quad * 8];
#pragma unroll
        for (int cb = 0; cb < 2; cb++) {
          Cn[cb] = __builtin_amdgcn_mfma_f32_16x16x32_bf16(rA, Bf[5][cb], Cn[cb], 0, 0, 0);
#pragma unroll
          for (int r = 0; r < 4; r++) {
            float n = tanh_(Cn[cb][r]);
            float h = hC[tt][cb][r];
            h = fmaf(Cz[cb][r], n - h, h) + h0C[tt][cb][r];
            hC[tt][cb][r] = h;
            u16 hb = f2bf(h);
            int g2 = trowv + r;
            shn[g2 * LDST + cb * 16 + l16] = hb;
            int p2 = (g2 * 205) >> 11;
            int nd = g2 - p2 * 10;
            hbf[((p2 * 2 + cb) * 32 + ((nd >> 3) << 4) + l16) * 8 + (nd & 7)] = hb;
          }
        }
      }
    }
    __syncthreads();   // h (rows + B-frags) visible for next layer / epilogue
  }

  // ---- epilogue: comb rows (coalesced 16B stores) ----
  if (tid < 160) {
    const uint4* src = (const uint4*)&shn[tid * LDST];
    uint4* dst = (uint4*)(comb + ((size_t)base * 10 + tid) * 32);
#pragma unroll
    for (int q4 = 0; q4 < 4; q4++) dst[q4] = src[q4];
  }
}

// ============================ K2/K3: MFMA GEMM ============================
__global__ __launch_bounds__(256, 2) void k_gemm_mfma(
    const u16* __restrict__ in, const u16* __restrict__ bpk,
    const float* __restrict__ bias, u16* __restrict__ out,
    int K, int N)
{
  int tid = threadIdx.x;
  int wv = tid >> 6;
  int lane = tid & 63;
  int quad = lane >> 4;
  int l16 = lane & 15;
  long row0 = (long)blockIdx.x * 64 + wv * 16;
  int col0 = blockIdx.y << 8;
  int ncb = N >> 4;
  int nk = K >> 5;

  f32x4 acc[16];
#pragma unroll
  for (int cb = 0; cb < 16; cb++) {
    float b = bias[col0 + cb * 16 + l16];
    acc[cb] = (f32x4){b, b, b, b};
  }

  const u16* arow = in + (row0 + l16) * K + quad * 8;
  for (int kb = 0; kb < nk; kb++) {
    bf16x8 af = *(const bf16x8*)(arow + kb * 32);
    const u16* bbase = bpk + ((long)(kb * ncb + (col0 >> 4)) * 64 + lane) * 8;
#pragma unroll
    for (int cb = 0; cb < 16; cb++) {
      bf16x8 bfv = *(const bf16x8*)(bbase + cb * 512);
      acc[cb] = __builtin_amdgcn_mfma_f32_16x16x32_bf16(af, bfv, acc[cb], 0, 0, 0);
    }
  }

#pragma unroll
  for (int cb = 0; cb < 16; cb++) {
#pragma unroll
    for (int r = 0; r < 4; r++) {
      long row = row0 + quad * 4 + r;
      out[row * N + col0 + cb * 16 + l16] = f2bf(acc[cb][r]);
    }
  }
}

// ============================ K4: MFMA GARU (96 steps) + classifier ============================
__global__ __launch_bounds__(512, 2) void k_garu_mfma(
    const u16* __restrict__ aa, const u16* __restrict__ ugpk,
    const float* __restrict__ wsf, float* __restrict__ outp)
{
  extern __shared__ u16 sm[];
  u16* sUgn = sm;                  // [16cb][8kb][64][8] (128 KB)
  u16* shA  = sm + 65536;          // h  A-frags
  u16* srs  = sm + 65536 + 4096;   // rs A-frags

  int tid = threadIdx.x;
  int w = tid >> 6;
  int lane = tid & 63;
  int quad = lane >> 4;
  int l16 = lane & 15;
  int row0 = blockIdx.x * 16;
  int c0 = w * 32;
  int cbase = w * 2;

  {
    const uint4* src = (const uint4*)(ugpk + 2 * 65536);
    uint4* dst = (uint4*)sUgn;
    for (int d = tid; d < 8192; d += 512) dst[d] = src[d];
  }
  ((uint4*)shA)[tid] = (uint4){0u, 0u, 0u, 0u};

  bf16x8 fz[2][8], fr[2][8];
#pragma unroll
  for (int cb2 = 0; cb2 < 2; cb2++) {
#pragma unroll
    for (int kb = 0; kb < 8; kb++) {
      fz[cb2][kb] = *(const bf16x8*)(ugpk + ((((cbase + cb2)) * 8 + kb) * 64 + lane) * 8);
      fr[cb2][kb] = *(const bf16x8*)(ugpk + (((16 + cbase + cb2) * 8 + kb) * 64 + lane) * 8);
    }
  }

  float hold[2][4];
#pragma unroll
  for (int cb2 = 0; cb2 < 2; cb2++)
#pragma unroll
    for (int r = 0; r < 4; r++) hold[cb2][r] = 0.f;

  int scat[2];
#pragma unroll
  for (int cb2 = 0; cb2 < 2; cb2++) {
    int col = c0 + cb2 * 16 + l16;
    scat[cb2] = (col >> 5) * 512 + ((col >> 3) & 3) * 128 + (quad * 4) * 8 + (col & 7);
  }

  __syncthreads();

  for (int st = 0; st < 96; st++) {
    const u16* ab = aa + ((size_t)st * 1024 + row0) * 768;

    float az[2][4], aR[2][4], an[2][4];
#pragma unroll
    for (int cb2 = 0; cb2 < 2; cb2++) {
      int col = c0 + cb2 * 16 + l16;
#pragma unroll
      for (int r = 0; r < 4; r++) {
        int row = quad * 4 + r;
        az[cb2][r] = bf2f(ab[row * 768 + col]);
        aR[cb2][r] = bf2f(ab[row * 768 + 256 + col]);
        an[cb2][r] = bf2f(ab[row * 768 + 512 + col]);
      }
    }

    f32x4 zero4 = (f32x4){0.f, 0.f, 0.f, 0.f};
    f32x4 uz0 = zero4, uz1 = zero4, ur0 = zero4, ur1 = zero4;
#pragma unroll
    for (int kb = 0; kb < 8; kb++) {
      bf16x8 hA = *(const bf16x8*)(shA + kb * 512 + lane * 8);
      uz0 = __builtin_amdgcn_mfma_f32_16x16x32_bf16(hA, fz[0][kb], uz0, 0, 0, 0);
      uz1 = __builtin_amdgcn_mfma_f32_16x16x32_bf16(hA, fz[1][kb], uz1, 0, 0, 0);
      ur0 = __builtin_amdgcn_mfma_f32_16x16x32_bf16(hA, fr[0][kb], ur0, 0, 0, 0);
      ur1 = __builtin_amdgcn_mfma_f32_16x16x32_bf16(hA, fr[1][kb], ur1, 0, 0, 0);
    }

#pragma unroll
    for (int r = 0; r < 4; r++) {
      float g0 = sigm(aR[0][r] + ur0[r]);
      float g1 = sigm(aR[1][r] + ur1[r]);
      srs[scat[0] + r * 8] = f2bf(g0 * hold[0][r]);
      srs[scat[1] + r * 8] = f2bf(g1 * hold[1][r]);
    }
    __syncthreads();

    f32x4 un0 = zero4, un1 = zero4;
#pragma unroll
    for (int kb = 0; kb < 8; kb++) {
      bf16x8 rA = *(const bf16x8*)(srs + kb * 512 + lane * 8);
      bf16x8 b0 = *(const bf16x8*)(sUgn + ((cbase + 0) * 8 + kb) * 512 + lane * 8);
      bf16x8 b1 = *(const bf16x8*)(sUgn + ((cbase + 1) * 8 + kb) * 512 + lane * 8);
      un0 = __builtin_amdgcn_mfma_f32_16x16x32_bf16(rA, b0, un0, 0, 0, 0);
      un1 = __builtin_amdgcn_mfma_f32_16x16x32_bf16(rA, b1, un1, 0, 0, 0);
    }

#pragma unroll
    for (int r = 0; r < 4; r++) {
      float gz0 = sigm(az[0][r] + uz0[r]);
      float gz1 = sigm(az[1][r] + uz1[r]);
      float gn0 = tanh_(an[0][r] + un0[r]);
      float gn1 = tanh_(an[1][r] + un1[r]);
      float h0n = fmaf(gz0, hold[0][r] - gn0, gn0);
      float h1n = fmaf(gz1, hold[1][r] - gn1, gn1);
      hold[0][r] = h0n;
      hold[1][r] = h1n;
      shA[scat[0] + r * 8] = f2bf(h0n);
      shA[scat[1] + r * 8] = f2bf(h1n);
    }
    __syncthreads();
  }

  const float* W1 = wsf + OFF_W1;
  const float* B1 = wsf + OFF_B1;
  const float* W2 = wsf + OFF_W2;
  const float* B2 = wsf + OFF_B2;
#pragma unroll
  for (int rloc = 0; rloc < 2; rloc++) {
    int rr = w * 2 + rloc;
    float hid = B1[lane];
    for (int c = 0; c < 256; c++) {
      int addr = (c >> 5) * 512 + ((c >> 3) & 3) * 128 + rr * 8 + (c & 7);
      hid = fmaf(bf2f(shA[addr]), W1[c * 64 + lane], hid);
    }
    hid = fmaxf(hid, 0.f);
    float v = hid * W2[lane];
#pragma unroll
    for (int off = 32; off > 0; off >>= 1) v += __shfl_xor(v, off, 64);
    if (lane == 0) outp[row0 + rr] = sigm(v + B2[0]);
  }
}

// ============================ launch ============================
extern "C" void kernel_launch(void* const* d_in, const int* in_sizes, int n_in,
                              void* d_out, int out_size, void* d_ws, size_t ws_size,
                              hipStream_t stream) {
  const void* x    = d_in[0];
  const void* adj  = d_in[1];
  const void* wfi  = d_in[2];
  const void* bfi  = d_in[3];
  const void* wz   = d_in[4];
  const void* uz   = d_in[5];
  const void* bz   = d_in[6];
  const void* wr   = d_in[7];
  const void* ur   = d_in[8];
  const void* br   = d_in[9];
  const void* wh   = d_in[10];
  const void* uh   = d_in[11];
  const void* bh   = d_in[12];
  const void* wgp  = d_in[13];
  const void* bgp  = d_in[14];
  const void* wgz  = d_in[15];
  const void* ugz  = d_in[16];
  const void* bgz  = d_in[17];
  const void* wgr  = d_in[18];
  const void* ugr  = d_in[19];
  const void* bgr  = d_in[20];
  const void* wgn  = d_in[21];
  const void* ugn  = d_in[22];
  const void* bgn  = d_in[23];

  float* wsf  = (float*)d_ws;
  u16* ugpk   = (u16*)((char*)d_ws + UGPK_BYTE);
  u16* bpk2   = (u16*)((char*)d_ws + BPK2_BYTE);
  u16* bpk3   = (u16*)((char*)d_ws + BPK3_BYTE);
  u16* gnnpk  = (u16*)((char*)d_ws + GNNPK_BYTE);
  u16* gi     = (u16*)((char*)d_ws + GI_BYTE);
  u16* comb   = (u16*)((char*)d_ws + X_BYTE);
  u16* aa     = (u16*)((char*)d_ws + X_BYTE);

  k_detect<<<1, 256, 0, stream>>>((const u32*)x, wsf);

  k_convert<<<(WF_TOTAL + 255) / 256, 256, 0, stream>>>(
      wfi, bfi, wz, uz, bz, wr, ur, br, wh, uh, bh,
      wgp, bgp, wgz, bgz, wgr, bgr, wgn, bgn, d_in[24], d_in[25], d_in[26], d_in[27], wsf);

  k_pack_ug<<<(196608 + 255) / 256, 256, 0, stream>>>(ugz, ugr, ugn, wsf, ugpk);

  k_pack<<<(81920 + 196608 + 255) / 256, 256, 0, stream>>>(
      wgp, wgz, wgr, wgn, wsf, bpk2, bpk3);

  k_pack_gnn<<<100, 256, 0, stream>>>(wfi, wz, uz, wr, ur, wh, uh, wsf, gnnpk);

  // K1: all 98304 problems -> comb
  k_gnn_mfma<<<TB_TOTAL / GP, 256, 0, stream>>>(x, adj, wsf, gnnpk, comb);

  // K2: gi = comb @ Wgp + bgp
  k_gemm_mfma<<<dim3(TB_TOTAL / 64, 1), 256, 0, stream>>>(
      comb, bpk2, wsf + OFF_BGP, gi, 320, 256);

  // K3: aa = gi @ [Wgz|Wgr|Wgn] + bgcat (writes X; comb dead)
  k_gemm_mfma<<<dim3(TB_TOTAL / 64, 3), 256, 0, stream>>>(
      gi, bpk3, wsf + OFF_BGCAT, aa, 256, 768);

  // K4: MFMA GARU over 96 steps + classifier -> d_out  (144 KB dynamic LDS)
  k_garu_mfma<<<64, 512, 147456, stream>>>(aa, ugpk, wsf, (float*)d_out);
}